// Round 5
// baseline (5203.297 us; speedup 1.0000x reference)
//
#include <hip/hip_runtime.h>
#include <cstddef>

typedef short bf16x8 __attribute__((ext_vector_type(8)));
typedef float f32x4 __attribute__((ext_vector_type(4)));

// fast sigmoid/tanh via v_exp_f32 + v_rcp_f32 (~1e-7 abs err, negligible vs bf16 h)
__device__ __forceinline__ float sigm(float x) {
    return __builtin_amdgcn_rcpf(1.f + __expf(-x));
}
__device__ __forceinline__ float ftanh(float x) {
    float e = __expf(2.f * x);
    return 1.f - 2.f * __builtin_amdgcn_rcpf(e + 1.f);
}

// f32 -> bf16 (round to nearest even)
__device__ __forceinline__ unsigned short f2bf(float f) {
    union { float f; unsigned u; } v; v.f = f;
    return (unsigned short)((v.u + 0x7FFFu + ((v.u >> 16) & 1u)) >> 16);
}

// lgkm-only barrier: LDS ordered, global loads/stores stay in flight (no vmcnt drain)
__device__ __forceinline__ void bar_lgkm() {
    asm volatile("s_waitcnt lgkmcnt(0)\ns_barrier" ::: "memory");
    __builtin_amdgcn_sched_barrier(0);
}

// ============================================================================
// prep_cast: one pass producing all bf16 operands.
// ============================================================================
#define N0 (20160 * 160)
#define N1 (2048 * 160)
#define N2 (2048 * 256)

__global__ __launch_bounds__(256) void prep_cast(
    const int* __restrict__ ids, const int* __restrict__ titles,
    const float* __restrict__ emb,
    const float* __restrict__ swf, const float* __restrict__ swb,
    const float* __restrict__ dwf, const float* __restrict__ dwb,
    unsigned* __restrict__ Abf, unsigned* __restrict__ Wsen,
    unsigned* __restrict__ Wdoc)
{
    int idx = blockIdx.x * 256 + threadIdx.x;
    if (idx < N0) {
        int row = idx / 160, kk = idx - row * 160;
        int id = (row < 19200) ? ids[row] : titles[row - 19200];
        float a = 0.f, b = 0.f;
        if (kk < 150) {
            const float* s = emb + (size_t)id * 300 + kk * 2;
            a = s[0]; b = s[1];
        }
        Abf[idx] = (unsigned)f2bf(a) | ((unsigned)f2bf(b) << 16);
    } else if (idx < N0 + N1) {
        int j = idx - N0;
        int row = j / 160, kk = j - row * 160;
        const float* base = (row < 1024) ? swf + (size_t)row * 300
                                         : swb + (size_t)(row - 1024) * 300;
        float a = 0.f, b = 0.f;
        if (kk < 150) { a = base[kk * 2]; b = base[kk * 2 + 1]; }
        Wsen[j] = (unsigned)f2bf(a) | ((unsigned)f2bf(b) << 16);
    } else if (idx < N0 + N1 + N2) {
        int j = idx - N0 - N1;
        int row = j >> 8, kk = j & 255;
        const float* base = (row < 1024) ? dwf + (size_t)row * 512
                                         : dwb + (size_t)(row - 1024) * 512;
        Wdoc[j] = (unsigned)f2bf(base[kk * 2]) | ((unsigned)f2bf(base[kk * 2 + 1]) << 16);
    }
}

// ============================================================================
// prep_whh: cast LSTM hidden weights to bf16, row-major [dir][1024][256].
// ============================================================================
__global__ __launch_bounds__(256) void prep_whh(
    const float* __restrict__ swf, const float* __restrict__ swb,
    const float* __restrict__ dwf, const float* __restrict__ dwb,
    unsigned* __restrict__ WS, unsigned* __restrict__ WD)
{
    int idx = blockIdx.x * 256 + threadIdx.x;   // 0 .. 524287
    const float* src; unsigned* dst;
    if (idx < 262144) {
        int j = idx; int dir = j >> 17; int rem = j & 131071;
        src = (dir ? swb : swf) + ((size_t)(rem >> 7) * 256 + (rem & 127) * 2);
        dst = WS + j;
    } else {
        int j = idx - 262144; int dir = j >> 17; int rem = j & 131071;
        src = (dir ? dwb : dwf) + ((size_t)(rem >> 7) * 256 + (rem & 127) * 2);
        dst = WD + j;
    }
    *dst = (unsigned)f2bf(src[0]) | ((unsigned)f2bf(src[1]) << 16);
}

// ============================================================================
// proj_mfma: out[M][2048] = Abf[M][Kp] @ Wbf^T + bias, output GATE-INTERLEAVED:
//   col = half*1024 + unit*4 + gate
// ============================================================================
__global__ __launch_bounds__(256) void proj_mfma(
    const unsigned short* __restrict__ Abf, int M, int Kp,
    const unsigned short* __restrict__ Wbf,
    const float* __restrict__ bf_, const float* __restrict__ bb_,
    float* __restrict__ out)
{
    __shared__ unsigned short As[128 * 40];   // pitch 80B (16B aligned)
    __shared__ unsigned short Ws[128 * 40];
    const int tid  = threadIdx.x;
    const int lane = tid & 63;
    const int w    = tid >> 6;
    const int n    = lane & 15;
    const int quad = lane >> 4;
    const int bm   = blockIdx.x * 128;
    const int by   = blockIdx.y;              // 0..15
    const int half = by >> 3;
    const int ug32 = (by & 7) * 32;
    const unsigned short* Wb = Wbf + (size_t)half * 1024 * Kp;
    const float* biasp = half ? bb_ : bf_;

    f32x4 acc[2][8];
#pragma unroll
    for (int rt = 0; rt < 2; rt++)
#pragma unroll
        for (int ct = 0; ct < 8; ct++) acc[rt][ct] = (f32x4){0.f, 0.f, 0.f, 0.f};

    const int chunks = Kp >> 5;
    for (int kc = 0; kc < chunks; kc++) {
        const int k0 = kc * 32;
#pragma unroll
        for (int j = 0; j < 2; j++) {
            int idx = j * 256 + tid;
            int arow = idx >> 2, qq = idx & 3;
            int grow = bm + arow; if (grow >= M) grow = M - 1;
            *(uint4*)&As[arow * 40 + qq * 8] =
                *(const uint4*)(Abf + (size_t)grow * Kp + k0 + qq * 8);
            int cc = idx >> 2;
            int wrow = (cc >> 5) * 256 + ug32 + (cc & 31);
            *(uint4*)&Ws[cc * 40 + qq * 8] =
                *(const uint4*)(Wb + (size_t)wrow * Kp + k0 + qq * 8);
        }
        __syncthreads();
        bf16x8 Aq[2], Bq[8];
#pragma unroll
        for (int rt = 0; rt < 2; rt++)
            Aq[rt] = *(const bf16x8*)&As[((w * 2 + rt) * 16 + n) * 40 + quad * 8];
#pragma unroll
        for (int ct = 0; ct < 8; ct++)
            Bq[ct] = *(const bf16x8*)&Ws[(ct * 16 + n) * 40 + quad * 8];
#pragma unroll
        for (int rt = 0; rt < 2; rt++)
#pragma unroll
            for (int ct = 0; ct < 8; ct++)
                acc[rt][ct] = __builtin_amdgcn_mfma_f32_16x16x32_bf16(
                    Aq[rt], Bq[ct], acc[rt][ct], 0, 0, 0);
        __syncthreads();
    }

#pragma unroll
    for (int s = 0; s < 2; s++) {
        const int uL = s * 16 + n;
        float b0 = biasp[ug32 + uL];
        float b1 = biasp[256 + ug32 + uL];
        float b2 = biasp[512 + ug32 + uL];
        float b3 = biasp[768 + ug32 + uL];
#pragma unroll
        for (int rt = 0; rt < 2; rt++) {
#pragma unroll
            for (int r = 0; r < 4; r++) {
                int row = bm + (w * 2 + rt) * 16 + quad * 4 + r;
                if (row >= M) continue;
                float4 o;
                o.x = acc[rt][0 + s][r] + b0;
                o.y = acc[rt][2 + s][r] + b1;
                o.z = acc[rt][4 + s][r] + b2;
                o.w = acc[rt][6 + s][r] + b3;
                *(float4*)(out + (size_t)row * 2048 + half * 1024 + (ug32 + uL) * 4) = o;
            }
        }
    }
}

__device__ __forceinline__ const float* sen_xbase(
    const float* xw, const float* xw_head, int grow_e, int t)
{
    if (grow_e < 640)       return xw + ((size_t)grow_e * 30 + t) * 2048;
    else if (grow_e < 1280) return xw + ((size_t)(grow_e - 640) * 30 + 29 - t) * 2048 + 1024;
    else if (grow_e < 1344) return xw_head + ((size_t)(grow_e - 1280) * 15 + t) * 2048;
    else                    return xw_head + ((size_t)(grow_e - 1344) * 15 + 14 - t) * 2048 + 1024;
}

// ============================================================================
// lstm_sen4: persistent BiLSTM, 88 pair-groups x 2 blocks x 512 thr.
// Per step: own h-half in LDS; partner half loaded DIRECTLY into MFMA A-frags
// from global (relaxed agent atomics). Sync = monotonic counter; per-wave
// increments after per-wave vmcnt drain; THROTTLED single poller (tid 0 +
// s_sleep) releases the block via an lgkm-only barrier (R4's all-thread spin
// collapsed the fabric: 1.1 GB poll FETCH). Barriers never drain vmcnt, so
// xw prefetch + partner loads stay in flight across them.
// ============================================================================
__global__ __launch_bounds__(512, 2) void lstm_sen4(
    const float* __restrict__ xw, const float* __restrict__ xw_head,
    const unsigned short* __restrict__ WhhBf,     // [2][1024][256] bf16
    unsigned short* hbA, unsigned short* hbB,
    float* __restrict__ sentences, float* __restrict__ headings,
    unsigned* bars)
{
    const int tid  = threadIdx.x;
    const int lane = tid & 63;
    const int w    = tid >> 6;          // 0..7
    const int n    = lane & 15;
    const int quad = lane >> 4;
    const int phys = blockIdx.x;        // 0..175
    const int g    = (phys & 7) + (phys >> 4) * 8;   // 0..87
    const int p    = (phys >> 3) & 1;                // unit-half
    const int r0   = g * 16;
    const bool bwd  = (r0 >= 640 && r0 < 1280) || (r0 >= 1344);
    const bool head = (r0 >= 1280);
    const int tEnd = head ? 15 : 30;
    unsigned* cnt = bars + g * 16;
    const unsigned short* Wd = WhhBf + (bwd ? (size_t)262144 : 0);

    __shared__ unsigned short Hs[16][136];      // own half only, pitch 272B
    __shared__ float G[16][516];

    // B fragments: wave w owns local cols w*64 + ct*16 + n
    bf16x8 Bf[4][8];
#pragma unroll
    for (int ct = 0; ct < 4; ct++) {
        const int c    = ct * 16 + n;
        const int unit = p * 128 + w * 16 + (c >> 2);
        const int wrow = (c & 3) * 256 + unit;
        const unsigned short* wr = Wd + (size_t)wrow * 256;
#pragma unroll
        for (int ks = 0; ks < 8; ks++)
            Bf[ct][ks] = *(const bf16x8*)(wr + ks * 32 + quad * 8);
    }

    const int rE  = tid & 15;
    const int iE  = tid >> 4;            // 0..31
    const int ug4 = p * 128 + iE * 4;
    const int grow_e = r0 + rE;
    float cr[4] = {0.f, 0.f, 0.f, 0.f};

    // pointer-stepped xw prefetch
    const float* xptr = sen_xbase(xw, xw_head, grow_e, 0) + (size_t)ug4 * 4;
    const long long xstep = bwd ? -2048 : 2048;
    float4 xv[4];
    { const float4* xp = (const float4*)xptr;
      xv[0] = xp[0]; xv[1] = xp[1]; xv[2] = xp[2]; xv[3] = xp[3]; }

    // final h destination
    float* fdst;
    if (!head) fdst = sentences + (size_t)(bwd ? grow_e - 640 : grow_e) * 512
                      + (bwd ? 256 : 0) + ug4;
    else       fdst = headings + (size_t)(grow_e - (bwd ? 1344 : 1280)) * 512
                      + (bwd ? 256 : 0) + ug4;

    // h global store/load bases (double-buffered)
    unsigned long long* hst[2] = {
        (unsigned long long*)(hbB + (size_t)grow_e * 256 + ug4),
        (unsigned long long*)(hbA + (size_t)grow_e * 256 + ug4) };
    const unsigned long long* pld[2] = {
        (const unsigned long long*)(hbB + (size_t)(r0 + n) * 256),
        (const unsigned long long*)(hbA + (size_t)(r0 + n) * 256) };

    for (int t = 0; t < tEnd; t++) {
        if (t > 0) {
            // ---- throttled wait for partner h(t) (stored during iter t-1) ----
            if (tid == 0) {
                const unsigned tgt = 16u * (unsigned)t;
                while (__hip_atomic_load(cnt, __ATOMIC_RELAXED,
                                         __HIP_MEMORY_SCOPE_AGENT) < tgt)
                    __builtin_amdgcn_s_sleep(1);
            }
            bar_lgkm();       // release block; orders Hs(t-1 write)->read, G reuse
            // ---- partner half -> Af regs (in flight during own-half MFMAs) ----
            bf16x8 Af[8];
            const unsigned long long* pb = pld[(t + 1) & 1];
#pragma unroll
            for (int k2 = 0; k2 < 4; k2++) {
                const int ksp = 4 * (1 - p) + k2;
                union { bf16x8 v; unsigned long long q[2]; } af;
                af.q[0] = __hip_atomic_load(pb + ksp * 8 + quad * 2,
                                            __ATOMIC_RELAXED, __HIP_MEMORY_SCOPE_AGENT);
                af.q[1] = __hip_atomic_load(pb + ksp * 8 + quad * 2 + 1,
                                            __ATOMIC_RELAXED, __HIP_MEMORY_SCOPE_AGENT);
                Af[ksp] = af.v;
            }
            // own half from LDS
#pragma unroll
            for (int k2 = 0; k2 < 4; k2++)
                Af[4 * p + k2] = *(const bf16x8*)&Hs[n][k2 * 32 + quad * 8];

            f32x4 acc[4];
#pragma unroll
            for (int ct = 0; ct < 4; ct++) acc[ct] = (f32x4){0.f, 0.f, 0.f, 0.f};
            // own-ks first (overlap partner-load latency)
#pragma unroll
            for (int k2 = 0; k2 < 4; k2++)
#pragma unroll
                for (int ct = 0; ct < 4; ct++)
                    acc[ct] = __builtin_amdgcn_mfma_f32_16x16x32_bf16(
                        Af[4 * p + k2], Bf[ct][4 * p + k2], acc[ct], 0, 0, 0);
#pragma unroll
            for (int k2 = 0; k2 < 4; k2++)
#pragma unroll
                for (int ct = 0; ct < 4; ct++)
                    acc[ct] = __builtin_amdgcn_mfma_f32_16x16x32_bf16(
                        Af[4 * (1 - p) + k2], Bf[ct][4 * (1 - p) + k2], acc[ct], 0, 0, 0);
#pragma unroll
            for (int ct = 0; ct < 4; ct++)
#pragma unroll
                for (int r = 0; r < 4; r++)
                    G[quad * 4 + r][w * 64 + ct * 16 + n] = acc[ct][r];
            bar_lgkm();       // G written -> readable
        }

        // ---- gate epilogue: 4 (row,unit) pairs per thread ----
        {
            const float4* Gp = (const float4*)&G[rE][iE * 16];
            unsigned long long hpack = 0ull;
            float hout[4];
#pragma unroll
            for (int q2 = 0; q2 < 4; q2++) {
                float4 gv;
                if (t == 0) gv = (float4){0.f, 0.f, 0.f, 0.f};
                else        gv = Gp[q2];
                float gi = gv.x + xv[q2].x;
                float gf = gv.y + xv[q2].y;
                float gg = gv.z + xv[q2].z;
                float go = gv.w + xv[q2].w;
                float cn = sigm(gf) * cr[q2] + sigm(gi) * ftanh(gg);
                float hn = sigm(go) * ftanh(cn);
                cr[q2] = cn; hout[q2] = hn;
                hpack |= ((unsigned long long)f2bf(hn)) << (16 * q2);
            }
            *(unsigned long long*)&Hs[rE][iE * 4] = hpack;     // own half -> LDS
            __hip_atomic_store(hst[t & 1], hpack,
                               __ATOMIC_RELAXED, __HIP_MEMORY_SCOPE_AGENT);
            if (t == tEnd - 1) *(float4*)fdst = *(float4*)hout;
        }

        // per-wave store drain, then signal
        asm volatile("s_waitcnt vmcnt(0)" ::: "memory");
        if (lane == 0)
            __hip_atomic_fetch_add(cnt, 1u, __ATOMIC_RELAXED, __HIP_MEMORY_SCOPE_AGENT);

        // xw prefetch for t+1 (issued after drain -> stays in flight)
        if (t + 1 < tEnd) {
            xptr += xstep;
            const float4* xp = (const float4*)xptr;
            xv[0] = xp[0]; xv[1] = xp[1]; xv[2] = xp[2]; xv[3] = xp[3];
        }
    }
}

// ============================================================================
// lstm_doc4: same structure, 8 pair-groups, 10 steps. Grid 16 x 512.
// ============================================================================
__global__ __launch_bounds__(512, 2) void lstm_doc4(
    const float* __restrict__ xw,
    const unsigned short* __restrict__ WhhBf,
    unsigned short* hdA, unsigned short* hdB,
    float* __restrict__ documents,
    unsigned* bars)
{
    const int tid  = threadIdx.x;
    const int lane = tid & 63;
    const int w    = tid >> 6;
    const int n    = lane & 15;
    const int quad = lane >> 4;
    const int phys = blockIdx.x;        // 0..15
    const int g    = phys & 7;
    const int p    = (phys >> 3) & 1;
    const int r0   = g * 16;
    const bool bwd = (r0 >= 64);
    unsigned* cnt = bars + g * 16;
    const unsigned short* Wd = WhhBf + (bwd ? (size_t)262144 : 0);

    __shared__ unsigned short Hs[16][136];
    __shared__ float G[16][516];

    bf16x8 Bf[4][8];
#pragma unroll
    for (int ct = 0; ct < 4; ct++) {
        const int c    = ct * 16 + n;
        const int unit = p * 128 + w * 16 + (c >> 2);
        const int wrow = (c & 3) * 256 + unit;
        const unsigned short* wr = Wd + (size_t)wrow * 256;
#pragma unroll
        for (int ks = 0; ks < 8; ks++)
            Bf[ct][ks] = *(const bf16x8*)(wr + ks * 32 + quad * 8);
    }

    const int rE  = tid & 15;
    const int iE  = tid >> 4;
    const int ug4 = p * 128 + iE * 4;
    const int grow_e = r0 + rE;
    const int seq = bwd ? grow_e - 64 : grow_e;
    float cr[4] = {0.f, 0.f, 0.f, 0.f};

    const float* xptr = (!bwd ? xw + (size_t)seq * 10 * 2048
                              : xw + ((size_t)seq * 10 + 9) * 2048 + 1024)
                        + (size_t)ug4 * 4;
    const long long xstep = bwd ? -2048 : 2048;
    float4 xv[4];
    { const float4* xp = (const float4*)xptr;
      xv[0] = xp[0]; xv[1] = xp[1]; xv[2] = xp[2]; xv[3] = xp[3]; }

    float* dptr = documents + (size_t)(seq * 10 + (bwd ? 9 : 0)) * 512
                  + (bwd ? 256 : 0) + ug4;
    const long long dstep = bwd ? -512 : 512;

    unsigned long long* hst[2] = {
        (unsigned long long*)(hdB + (size_t)grow_e * 256 + ug4),
        (unsigned long long*)(hdA + (size_t)grow_e * 256 + ug4) };
    const unsigned long long* pld[2] = {
        (const unsigned long long*)(hdB + (size_t)(r0 + n) * 256),
        (const unsigned long long*)(hdA + (size_t)(r0 + n) * 256) };

    for (int t = 0; t < 10; t++) {
        if (t > 0) {
            if (tid == 0) {
                const unsigned tgt = 16u * (unsigned)t;
                while (__hip_atomic_load(cnt, __ATOMIC_RELAXED,
                                         __HIP_MEMORY_SCOPE_AGENT) < tgt)
                    __builtin_amdgcn_s_sleep(1);
            }
            bar_lgkm();
            bf16x8 Af[8];
            const unsigned long long* pb = pld[(t + 1) & 1];
#pragma unroll
            for (int k2 = 0; k2 < 4; k2++) {
                const int ksp = 4 * (1 - p) + k2;
                union { bf16x8 v; unsigned long long q[2]; } af;
                af.q[0] = __hip_atomic_load(pb + ksp * 8 + quad * 2,
                                            __ATOMIC_RELAXED, __HIP_MEMORY_SCOPE_AGENT);
                af.q[1] = __hip_atomic_load(pb + ksp * 8 + quad * 2 + 1,
                                            __ATOMIC_RELAXED, __HIP_MEMORY_SCOPE_AGENT);
                Af[ksp] = af.v;
            }
#pragma unroll
            for (int k2 = 0; k2 < 4; k2++)
                Af[4 * p + k2] = *(const bf16x8*)&Hs[n][k2 * 32 + quad * 8];

            f32x4 acc[4];
#pragma unroll
            for (int ct = 0; ct < 4; ct++) acc[ct] = (f32x4){0.f, 0.f, 0.f, 0.f};
#pragma unroll
            for (int k2 = 0; k2 < 4; k2++)
#pragma unroll
                for (int ct = 0; ct < 4; ct++)
                    acc[ct] = __builtin_amdgcn_mfma_f32_16x16x32_bf16(
                        Af[4 * p + k2], Bf[ct][4 * p + k2], acc[ct], 0, 0, 0);
#pragma unroll
            for (int k2 = 0; k2 < 4; k2++)
#pragma unroll
                for (int ct = 0; ct < 4; ct++)
                    acc[ct] = __builtin_amdgcn_mfma_f32_16x16x32_bf16(
                        Af[4 * (1 - p) + k2], Bf[ct][4 * (1 - p) + k2], acc[ct], 0, 0, 0);
#pragma unroll
            for (int ct = 0; ct < 4; ct++)
#pragma unroll
                for (int r = 0; r < 4; r++)
                    G[quad * 4 + r][w * 64 + ct * 16 + n] = acc[ct][r];
            bar_lgkm();
        }

        {
            const float4* Gp = (const float4*)&G[rE][iE * 16];
            unsigned long long hpack = 0ull;
            float hout[4];
#pragma unroll
            for (int q2 = 0; q2 < 4; q2++) {
                float4 gv;
                if (t == 0) gv = (float4){0.f, 0.f, 0.f, 0.f};
                else        gv = Gp[q2];
                float gi = gv.x + xv[q2].x;
                float gf = gv.y + xv[q2].y;
                float gg = gv.z + xv[q2].z;
                float go = gv.w + xv[q2].w;
                float cn = sigm(gf) * cr[q2] + sigm(gi) * ftanh(gg);
                float hn = sigm(go) * ftanh(cn);
                cr[q2] = cn; hout[q2] = hn;
                hpack |= ((unsigned long long)f2bf(hn)) << (16 * q2);
            }
            *(unsigned long long*)&Hs[rE][iE * 4] = hpack;
            __hip_atomic_store(hst[t & 1], hpack,
                               __ATOMIC_RELAXED, __HIP_MEMORY_SCOPE_AGENT);
            *(float4*)dptr = *(float4*)hout;
        }

        asm volatile("s_waitcnt vmcnt(0)" ::: "memory");
        if (lane == 0)
            __hip_atomic_fetch_add(cnt, 1u, __ATOMIC_RELAXED, __HIP_MEMORY_SCOPE_AGENT);

        if (t < 9) {
            xptr += xstep;  dptr += dstep;
            const float4* xp = (const float4*)xptr;
            xv[0] = xp[0]; xv[1] = xp[1]; xv[2] = xp[2]; xv[3] = xp[3];
        }
    }
}

// SourceBias: biasedBf[t] = bf16(tanh(sen[t] @ trans[u] + sb_bias[u]))
__global__ __launch_bounds__(256) void source_bias(
    const float* __restrict__ sentences, const int* __restrict__ urls,
    const float* __restrict__ trans, const float* __restrict__ sb_bias,
    unsigned* __restrict__ biasedBf)
{
    const int tkn = blockIdx.x;
    const int u = urls[tkn];
    const float2* Tm = (const float2*)(trans + (size_t)u * 512 * 512);
    __shared__ float sv[512];
    for (int i = threadIdx.x; i < 512; i += 256) sv[i] = sentences[(size_t)tkn * 512 + i];
    __syncthreads();
    const int e = threadIdx.x;
    float ax = 0.f, ay = 0.f;
#pragma unroll 4
    for (int d = 0; d < 512; d++) {
        float s = sv[d];
        float2 tv = Tm[(size_t)d * 256 + e];
        ax += s * tv.x; ay += s * tv.y;
    }
    const float2 bv = ((const float2*)(sb_bias + (size_t)u * 512))[e];
    float x = ftanh(ax + bv.x), y = ftanh(ay + bv.y);
    biasedBf[(size_t)tkn * 256 + e] = (unsigned)f2bf(x) | ((unsigned)f2bf(y) << 16);
}

// v[b,d] = sum_e attn_W[d,e] * heading[b,e]; block per b
__global__ __launch_bounds__(256) void attn_v(
    const float* __restrict__ W, const float* __restrict__ headings,
    float* __restrict__ v)
{
    const int b = blockIdx.x;
    __shared__ float hh[512];
    for (int i = threadIdx.x; i < 512; i += 256) hh[i] = headings[(size_t)b * 512 + i];
    __syncthreads();
    for (int d = threadIdx.x; d < 512; d += 256) {
        float a = 0.f;
        const float* wr = W + (size_t)d * 512;
        for (int e = 0; e < 512; e++) a += wr[e] * hh[e];
        v[(size_t)b * 512 + d] = a;
    }
}

// scores -> softmax -> doc_rep -> both MLP heads; block per batch element
__global__ __launch_bounds__(256) void attn_heads(
    const float* __restrict__ documents, const float* __restrict__ v,
    const float* __restrict__ attn_b,
    const float* __restrict__ bW1, const float* __restrict__ bb1,
    const float* __restrict__ bW2, const float* __restrict__ bb2,
    const float* __restrict__ tW1, const float* __restrict__ tb1,
    const float* __restrict__ tW2, const float* __restrict__ tb2,
    float* __restrict__ out)
{
    const int b = blockIdx.x, tid = threadIdx.x;
    const int lane = tid & 63, wv_ = tid >> 6;
    __shared__ float vv[512], dr[512], h1s[256], t1s[256], sw[12], lg[5];
    for (int i = tid; i < 512; i += 256) vv[i] = v[(size_t)b * 512 + i];
    __syncthreads();
    for (int q = 0; q < 3; q++) {
        int s = q * 4 + wv_;
        float p = 0.f;
        if (s < 10) {
            const float* dp = documents + (size_t)(b * 10 + s) * 512;
            for (int d = lane; d < 512; d += 64) p += dp[d] * vv[d];
        }
#pragma unroll
        for (int off = 32; off > 0; off >>= 1) p += __shfl_down(p, off, 64);
        if (s < 10 && lane == 0) sw[s] = p + attn_b[0];
    }
    __syncthreads();
    if (tid == 0) {
        float mx = sw[0];
        for (int s = 1; s < 10; s++) mx = fmaxf(mx, sw[s]);
        float sum = 0.f;
        for (int s = 0; s < 10; s++) { sw[s] = expf(sw[s] - mx); sum += sw[s]; }
        for (int s = 0; s < 10; s++) sw[s] /= sum;
    }
    __syncthreads();
    for (int d = tid; d < 512; d += 256) {
        float a = 0.f;
#pragma unroll
        for (int s = 0; s < 10; s++) a += sw[s] * documents[(size_t)(b * 10 + s) * 512 + d];
        dr[d] = a;
    }
    __syncthreads();
    {
        float a = bb1[tid], a2 = tb1[tid];
        const float* w1 = bW1 + (size_t)tid * 512;
        const float* w2 = tW1 + (size_t)tid * 512;
        for (int k = 0; k < 512; k++) { float x = dr[k]; a += x * w1[k]; a2 += x * w2[k]; }
        h1s[tid] = ftanh(a); t1s[tid] = ftanh(a2);
    }
    __syncthreads();
    if (tid < 5) {
        float a = bb2[tid];
        const float* wp = bW2 + (size_t)tid * 256;
        for (int k = 0; k < 256; k++) a += h1s[k] * wp[k];
        lg[tid] = ftanh(a);
    }
    if (tid == 32) {
        float a = tb2[0];
        for (int k = 0; k < 256; k++) a += t1s[k] * tW2[k];
        out[320 + b] = 1.f / (1.f + expf(-ftanh(a)));
    }
    __syncthreads();
    if (tid == 0) {
        float mx = lg[0];
        for (int j = 1; j < 5; j++) mx = fmaxf(mx, lg[j]);
        float sum = 0.f, e[5];
        for (int j = 0; j < 5; j++) { e[j] = expf(lg[j] - mx); sum += e[j]; }
        for (int j = 0; j < 5; j++) out[b * 5 + j] = e[j] / sum;
    }
}

extern "C" void kernel_launch(void* const* d_in, const int* in_sizes, int n_in,
                              void* d_out, int out_size, void* d_ws, size_t ws_size,
                              hipStream_t stream)
{
    (void)in_sizes; (void)n_in; (void)out_size; (void)ws_size;
    const int*   input_ids = (const int*)d_in[0];
    const int*   urls      = (const int*)d_in[1];
    const int*   titles    = (const int*)d_in[2];
    const float* emb       = (const float*)d_in[3];
    const float* sen_wih_f = (const float*)d_in[4];
    const float* sen_whh_f = (const float*)d_in[5];
    const float* sen_b_f   = (const float*)d_in[6];
    const float* sen_wih_b = (const float*)d_in[7];
    const float* sen_whh_b = (const float*)d_in[8];
    const float* sen_b_b   = (const float*)d_in[9];
    const float* trans     = (const float*)d_in[10];
    const float* sb_bias   = (const float*)d_in[11];
    const float* doc_wih_f = (const float*)d_in[12];
    const float* doc_whh_f = (const float*)d_in[13];
    const float* doc_b_f   = (const float*)d_in[14];
    const float* doc_wih_b = (const float*)d_in[15];
    const float* doc_whh_b = (const float*)d_in[16];
    const float* doc_b_b   = (const float*)d_in[17];
    const float* attn_W    = (const float*)d_in[18];
    const float* attn_b    = (const float*)d_in[19];
    const float* bias_W1   = (const float*)d_in[20];
    const float* bias_b1   = (const float*)d_in[21];
    const float* bias_W2   = (const float*)d_in[22];
    const float* bias_b2   = (const float*)d_in[23];
    const float* truth_W1  = (const float*)d_in[24];
    const float* truth_b1  = (const float*)d_in[25];
    const float* truth_W2  = (const float*)d_in[26];
    const float* truth_b2  = (const float*)d_in[27];
    float* out = (float*)d_out;

    float* ws = (float*)d_ws;
    float* xw_all      = ws;
    float* xw_head     = xw_all + (size_t)19200 * 2048;
    unsigned* biasedBf = (unsigned*)(ws + 0);
    float* xw_doc      = ws + 163840;
    float* documents   = ws + 1474560;
    float* vbuf        = ws + 1802240;

    float* slotB       = ws + 41287680;
    unsigned* Abf      = (unsigned*)slotB;
    float* sentences   = slotB;
    float* headings    = slotB + 327680;
    unsigned* WhhSbf   = (unsigned*)(slotB + 360448);   // [2][1024][128] u32
    unsigned* WhhDbf   = (unsigned*)(slotB + 622592);
    unsigned short* hbA = (unsigned short*)(slotB + 884736);
    unsigned short* hbB = (unsigned short*)(slotB + 1064960);
    unsigned short* hdA = (unsigned short*)(slotB + 1245184);
    unsigned short* hdB = (unsigned short*)(slotB + 1261568);
    unsigned* barsS    = (unsigned*)(slotB + 1277952);  // 88 pair counters
    unsigned* barsD    = barsS + 88 * 16;               // 8 pair counters

    unsigned* Wsen     = (unsigned*)(ws + 44513280);
    unsigned* Wdoc     = (unsigned*)(ws + 44840960);

    dim3 blk(256);

    // D1: gather + bf16 casts
    prep_cast<<<dim3((N0 + N1 + N2 + 255) / 256), blk, 0, stream>>>(
        input_ids, titles, emb, sen_wih_f, sen_wih_b, doc_wih_f, doc_wih_b,
        Abf, Wsen, Wdoc);

    // D2: sentence+title input projection
    proj_mfma<<<dim3(158, 16), blk, 0, stream>>>(
        (const unsigned short*)Abf, 20160, 320,
        (const unsigned short*)Wsen, sen_b_f, sen_b_b, xw_all);

    // bars zero + Whh bf16 cast (slot B dead after D2)
    hipMemsetAsync(barsS, 0, (88 + 8) * 16 * sizeof(unsigned), stream);
    prep_whh<<<dim3(2048), blk, 0, stream>>>(
        sen_whh_f, sen_whh_b, doc_whh_f, doc_whh_b, WhhSbf, WhhDbf);

    // D3: persistent sentence/heading BiLSTM
    lstm_sen4<<<dim3(176), dim3(512), 0, stream>>>(
        xw_all, xw_head, (const unsigned short*)WhhSbf, hbA, hbB,
        sentences, headings, barsS);

    // D4: SourceBias
    source_bias<<<dim3(640), blk, 0, stream>>>(sentences, urls, trans, sb_bias, biasedBf);

    // D5: document input projection
    proj_mfma<<<dim3(5, 16), blk, 0, stream>>>(
        (const unsigned short*)biasedBf, 640, 512,
        (const unsigned short*)Wdoc, doc_b_f, doc_b_b, xw_doc);

    // D6: persistent document BiLSTM
    lstm_doc4<<<dim3(16), dim3(512), 0, stream>>>(
        xw_doc, (const unsigned short*)WhhDbf, hdA, hdB, documents, barsD);

    // D7/D8: attention + heads
    attn_v<<<dim3(64), blk, 0, stream>>>(attn_W, headings, vbuf);
    attn_heads<<<dim3(64), blk, 0, stream>>>(documents, vbuf, attn_b,
                                             bias_W1, bias_b1, bias_W2, bias_b2,
                                             truth_W1, truth_b1, truth_W2, truth_b2,
                                             out);
}

// Round 7
// 562.970 us; speedup vs baseline: 9.2426x; 9.2426x over previous
//
#include <hip/hip_runtime.h>
#include <cstddef>

typedef short bf16x8 __attribute__((ext_vector_type(8)));
typedef float f32x4 __attribute__((ext_vector_type(4)));

// fast sigmoid/tanh via v_exp_f32 + v_rcp_f32 (~1e-7 abs err; validated R4/R5:
// absmax identical to libm build)
__device__ __forceinline__ float sigm(float x) {
    return __builtin_amdgcn_rcpf(1.f + __expf(-x));
}
__device__ __forceinline__ float ftanh(float x) {
    float e = __expf(2.f * x);
    return 1.f - 2.f * __builtin_amdgcn_rcpf(e + 1.f);
}

// f32 -> bf16 (round to nearest even)
__device__ __forceinline__ unsigned short f2bf(float f) {
    union { float f; unsigned u; } v; v.f = f;
    return (unsigned short)((v.u + 0x7FFFu + ((v.u >> 16) & 1u)) >> 16);
}

// ============================================================================
// prep_cast: one pass producing all bf16 operands.
// ============================================================================
#define N0 (20160 * 160)
#define N1 (2048 * 160)
#define N2 (2048 * 256)

__global__ __launch_bounds__(256) void prep_cast(
    const int* __restrict__ ids, const int* __restrict__ titles,
    const float* __restrict__ emb,
    const float* __restrict__ swf, const float* __restrict__ swb,
    const float* __restrict__ dwf, const float* __restrict__ dwb,
    unsigned* __restrict__ Abf, unsigned* __restrict__ Wsen,
    unsigned* __restrict__ Wdoc)
{
    int idx = blockIdx.x * 256 + threadIdx.x;
    if (idx < N0) {
        int row = idx / 160, kk = idx - row * 160;
        int id = (row < 19200) ? ids[row] : titles[row - 19200];
        float a = 0.f, b = 0.f;
        if (kk < 150) {
            const float* s = emb + (size_t)id * 300 + kk * 2;
            a = s[0]; b = s[1];
        }
        Abf[idx] = (unsigned)f2bf(a) | ((unsigned)f2bf(b) << 16);
    } else if (idx < N0 + N1) {
        int j = idx - N0;
        int row = j / 160, kk = j - row * 160;
        const float* base = (row < 1024) ? swf + (size_t)row * 300
                                         : swb + (size_t)(row - 1024) * 300;
        float a = 0.f, b = 0.f;
        if (kk < 150) { a = base[kk * 2]; b = base[kk * 2 + 1]; }
        Wsen[j] = (unsigned)f2bf(a) | ((unsigned)f2bf(b) << 16);
    } else if (idx < N0 + N1 + N2) {
        int j = idx - N0 - N1;
        int row = j >> 8, kk = j & 255;
        const float* base = (row < 1024) ? dwf + (size_t)row * 512
                                         : dwb + (size_t)(row - 1024) * 512;
        Wdoc[j] = (unsigned)f2bf(base[kk * 2]) | ((unsigned)f2bf(base[kk * 2 + 1]) << 16);
    }
}

// ============================================================================
// prep_whh: cast LSTM hidden weights to bf16, row-major [dir][1024][256].
// ============================================================================
__global__ __launch_bounds__(256) void prep_whh(
    const float* __restrict__ swf, const float* __restrict__ swb,
    const float* __restrict__ dwf, const float* __restrict__ dwb,
    unsigned* __restrict__ WS, unsigned* __restrict__ WD)
{
    int idx = blockIdx.x * 256 + threadIdx.x;   // 0 .. 524287
    const float* src; unsigned* dst;
    if (idx < 262144) {
        int j = idx; int dir = j >> 17; int rem = j & 131071;
        src = (dir ? swb : swf) + ((size_t)(rem >> 7) * 256 + (rem & 127) * 2);
        dst = WS + j;
    } else {
        int j = idx - 262144; int dir = j >> 17; int rem = j & 131071;
        src = (dir ? dwb : dwf) + ((size_t)(rem >> 7) * 256 + (rem & 127) * 2);
        dst = WD + j;
    }
    *dst = (unsigned)f2bf(src[0]) | ((unsigned)f2bf(src[1]) << 16);
}

// ============================================================================
// proj_mfma: out[M][2048] = Abf[M][Kp] @ Wbf^T + bias, output GATE-INTERLEAVED:
//   col = half*1024 + unit*4 + gate
// ============================================================================
__global__ __launch_bounds__(256) void proj_mfma(
    const unsigned short* __restrict__ Abf, int M, int Kp,
    const unsigned short* __restrict__ Wbf,
    const float* __restrict__ bf_, const float* __restrict__ bb_,
    float* __restrict__ out)
{
    __shared__ unsigned short As[128 * 40];   // pitch 80B (16B aligned)
    __shared__ unsigned short Ws[128 * 40];
    const int tid  = threadIdx.x;
    const int lane = tid & 63;
    const int w    = tid >> 6;
    const int n    = lane & 15;
    const int quad = lane >> 4;
    const int bm   = blockIdx.x * 128;
    const int by   = blockIdx.y;              // 0..15
    const int half = by >> 3;
    const int ug32 = (by & 7) * 32;
    const unsigned short* Wb = Wbf + (size_t)half * 1024 * Kp;
    const float* biasp = half ? bb_ : bf_;

    f32x4 acc[2][8];
#pragma unroll
    for (int rt = 0; rt < 2; rt++)
#pragma unroll
        for (int ct = 0; ct < 8; ct++) acc[rt][ct] = (f32x4){0.f, 0.f, 0.f, 0.f};

    const int chunks = Kp >> 5;
    for (int kc = 0; kc < chunks; kc++) {
        const int k0 = kc * 32;
#pragma unroll
        for (int j = 0; j < 2; j++) {
            int idx = j * 256 + tid;
            int arow = idx >> 2, qq = idx & 3;
            int grow = bm + arow; if (grow >= M) grow = M - 1;
            *(uint4*)&As[arow * 40 + qq * 8] =
                *(const uint4*)(Abf + (size_t)grow * Kp + k0 + qq * 8);
            int cc = idx >> 2;
            int wrow = (cc >> 5) * 256 + ug32 + (cc & 31);
            *(uint4*)&Ws[cc * 40 + qq * 8] =
                *(const uint4*)(Wb + (size_t)wrow * Kp + k0 + qq * 8);
        }
        __syncthreads();
        bf16x8 Aq[2], Bq[8];
#pragma unroll
        for (int rt = 0; rt < 2; rt++)
            Aq[rt] = *(const bf16x8*)&As[((w * 2 + rt) * 16 + n) * 40 + quad * 8];
#pragma unroll
        for (int ct = 0; ct < 8; ct++)
            Bq[ct] = *(const bf16x8*)&Ws[(ct * 16 + n) * 40 + quad * 8];
#pragma unroll
        for (int rt = 0; rt < 2; rt++)
#pragma unroll
            for (int ct = 0; ct < 8; ct++)
                acc[rt][ct] = __builtin_amdgcn_mfma_f32_16x16x32_bf16(
                    Aq[rt], Bq[ct], acc[rt][ct], 0, 0, 0);
        __syncthreads();
    }

#pragma unroll
    for (int s = 0; s < 2; s++) {
        const int uL = s * 16 + n;
        float b0 = biasp[ug32 + uL];
        float b1 = biasp[256 + ug32 + uL];
        float b2 = biasp[512 + ug32 + uL];
        float b3 = biasp[768 + ug32 + uL];
#pragma unroll
        for (int rt = 0; rt < 2; rt++) {
#pragma unroll
            for (int r = 0; r < 4; r++) {
                int row = bm + (w * 2 + rt) * 16 + quad * 4 + r;
                if (row >= M) continue;
                float4 o;
                o.x = acc[rt][0 + s][r] + b0;
                o.y = acc[rt][2 + s][r] + b1;
                o.z = acc[rt][4 + s][r] + b2;
                o.w = acc[rt][6 + s][r] + b3;
                *(float4*)(out + (size_t)row * 2048 + half * 1024 + (ug32 + uL) * 4) = o;
            }
        }
    }
}

// ---------------------------------------------------------------------------
// pair_sync (R3-proven): 2 blocks, MONOTONIC counter, relaxed agent atomics,
// thread0 increments + throttled poll. __syncthreads drains h-stores (vmcnt)
// before arrival.
// ---------------------------------------------------------------------------
__device__ __forceinline__ void pair_sync(unsigned* cnt, unsigned target) {
    __syncthreads();
    if (threadIdx.x == 0) {
        __hip_atomic_fetch_add(cnt, 1u, __ATOMIC_RELAXED, __HIP_MEMORY_SCOPE_AGENT);
        while (__hip_atomic_load(cnt, __ATOMIC_RELAXED, __HIP_MEMORY_SCOPE_AGENT) < target)
            __builtin_amdgcn_s_sleep(1);
    }
    __syncthreads();
}

__device__ __forceinline__ const float* sen_xbase(
    const float* xw, const float* xw_head, int grow_e, int t)
{
    if (grow_e < 640)       return xw + ((size_t)grow_e * 30 + t) * 2048;
    else if (grow_e < 1280) return xw + ((size_t)(grow_e - 640) * 30 + 29 - t) * 2048 + 1024;
    else if (grow_e < 1344) return xw_head + ((size_t)(grow_e - 1280) * 15 + t) * 2048;
    else                    return xw_head + ((size_t)(grow_e - 1344) * 15 + 14 - t) * 2048 + 1024;
}

// ============================================================================
// lstm_sen2b: R3's verified pair-structure (127 us) + fast transcendentals +
// pointer-stepped xw. Exchange skeleton UNCHANGED from R3: Hs double-buffer in
// LDS, partner half = ONE 8B agent-atomic load per thread per step (R4/R5's
// 8-per-thread operand-feed atomics caused a 10x fabric-traffic collapse).
// ============================================================================
__global__ __launch_bounds__(512, 2) void lstm_sen2b(
    const float* __restrict__ xw, const float* __restrict__ xw_head,
    const unsigned short* __restrict__ WhhBf,     // [2][1024][256] bf16
    unsigned short* hbA, unsigned short* hbB,
    float* __restrict__ sentences, float* __restrict__ headings,
    unsigned* bars)
{
    const int tid  = threadIdx.x;
    const int lane = tid & 63;
    const int w    = tid >> 6;          // 0..7 (wave)
    const int n    = lane & 15;
    const int quad = lane >> 4;
    const int phys = blockIdx.x;        // 0..175
    const int g    = (phys & 7) + (phys >> 4) * 8;   // 0..87 (pair group)
    const int p    = (phys >> 3) & 1;                // unit-half
    const int r0   = g * 16;
    const bool bwd  = (r0 >= 640 && r0 < 1280) || (r0 >= 1344);
    const bool head = (r0 >= 1280);
    const int tEnd = head ? 15 : 30;
    unsigned* cnt = bars + g * 16;      // 64B-separated counters
    const unsigned short* Wd = WhhBf + (bwd ? (size_t)262144 : 0);

    __shared__ unsigned short Hs[2][16][264];   // pitch 528B
    __shared__ float G[16][516];                // pitch 2064B

    // B fragments: wave w owns local cols w*64 + ct*16 + n
    bf16x8 Bf[4][8];
#pragma unroll
    for (int ct = 0; ct < 4; ct++) {
        const int c    = ct * 16 + n;
        const int unit = p * 128 + w * 16 + (c >> 2);
        const int wrow = (c & 3) * 256 + unit;
        const unsigned short* wr = Wd + (size_t)wrow * 256;
#pragma unroll
        for (int ks = 0; ks < 8; ks++)
            Bf[ct][ks] = *(const bf16x8*)(wr + ks * 32 + quad * 8);
    }

    // zero h(t=0)
    for (int i = tid; i < 16 * 264; i += 512) ((unsigned short*)Hs[0])[i] = 0;

    const int rE  = tid & 15;            // row within group
    const int iE  = tid >> 4;            // 0..31
    const int ug4 = p * 128 + iE * 4;    // global unit base (4 units/thread)
    const int grow_e = r0 + rE;
    float cr[4] = {0.f, 0.f, 0.f, 0.f};

    // pointer-stepped xw prefetch
    const float* xptr = sen_xbase(xw, xw_head, grow_e, 0) + (size_t)ug4 * 4;
    const long long xstep = bwd ? -2048 : 2048;
    float4 xv[4];
    { const float4* xp = (const float4*)xptr;
      xv[0] = xp[0]; xv[1] = xp[1]; xv[2] = xp[2]; xv[3] = xp[3]; }

    // final h destination
    float* fdst;
    if (!head) fdst = sentences + (size_t)(bwd ? grow_e - 640 : grow_e) * 512
                      + (bwd ? 256 : 0) + ug4;
    else       fdst = headings + (size_t)(grow_e - (bwd ? 1344 : 1280)) * 512
                      + (bwd ? 256 : 0) + ug4;

    __syncthreads();

    for (int t = 0; t < tEnd; t++) {
        const int cur = t & 1;
        unsigned short* hq = (t & 1) ? hbA : hbB;

        // ---- hidden GEMM: G[0..15][own 512 cols] = h(t) @ Whh-half ----
        {
            bf16x8 Af[8];
#pragma unroll
            for (int ks = 0; ks < 8; ks++)
                Af[ks] = *(const bf16x8*)&Hs[cur][n][ks * 32 + quad * 8];
            f32x4 acc[4];
#pragma unroll
            for (int ct = 0; ct < 4; ct++) acc[ct] = (f32x4){0.f, 0.f, 0.f, 0.f};
#pragma unroll
            for (int ks = 0; ks < 8; ks++)
#pragma unroll
                for (int ct = 0; ct < 4; ct++)
                    acc[ct] = __builtin_amdgcn_mfma_f32_16x16x32_bf16(
                        Af[ks], Bf[ct][ks], acc[ct], 0, 0, 0);
#pragma unroll
            for (int ct = 0; ct < 4; ct++)
#pragma unroll
                for (int r = 0; r < 4; r++)
                    G[quad * 4 + r][w * 64 + ct * 16 + n] = acc[ct][r];
        }
        __syncthreads();

        // ---- gate epilogue: 4 (row,unit) pairs per thread ----
        {
            const float4* Gp = (const float4*)&G[rE][iE * 16];
            unsigned long long hpack = 0ull;
            float hout[4];
#pragma unroll
            for (int q2 = 0; q2 < 4; q2++) {
                float4 gv = Gp[q2];
                float gi = gv.x + xv[q2].x;
                float gf = gv.y + xv[q2].y;
                float gg = gv.z + xv[q2].z;
                float go = gv.w + xv[q2].w;
                float cn = sigm(gf) * cr[q2] + sigm(gi) * ftanh(gg);
                float hn = sigm(go) * ftanh(cn);
                cr[q2] = cn; hout[q2] = hn;
                hpack |= ((unsigned long long)f2bf(hn)) << (16 * q2);
            }
            const int nxt = cur ^ 1;
            *(unsigned long long*)&Hs[nxt][rE][ug4] = hpack;   // own half -> LDS
            __hip_atomic_store((unsigned long long*)(hq + (size_t)grow_e * 256 + ug4),
                               hpack, __ATOMIC_RELAXED, __HIP_MEMORY_SCOPE_AGENT);
            if (t == tEnd - 1) *(float4*)fdst = *(float4*)hout;
        }

        if (t + 1 < tEnd) {
            // prefetch next step's xw BEFORE the sync wait (h-independent)
            xptr += xstep;
            const float4* xp = (const float4*)xptr;
            xv[0] = xp[0]; xv[1] = xp[1]; xv[2] = xp[2]; xv[3] = xp[3];
            pair_sync(cnt, 2u * (unsigned)(t + 1));
            // partner half -> Hs[nxt]: one 8B chunk per thread (16 rows x 32)
            {
                const int nxt   = cur ^ 1;
                const int row   = tid >> 5;
                const int chunk = tid & 31;
                const int pp    = p ^ 1;
                unsigned long long v = __hip_atomic_load(
                    (const unsigned long long*)(hq + (size_t)(r0 + row) * 256
                                                + pp * 128 + chunk * 4),
                    __ATOMIC_RELAXED, __HIP_MEMORY_SCOPE_AGENT);
                *(unsigned long long*)&Hs[nxt][row][pp * 128 + chunk * 4] = v;
            }
            __syncthreads();
        }
    }
}

// ============================================================================
// lstm_doc2b: same R3-proven structure, 8 pair-groups, 10 steps. Grid 16x512.
// ============================================================================
__global__ __launch_bounds__(512, 2) void lstm_doc2b(
    const float* __restrict__ xw,
    const unsigned short* __restrict__ WhhBf,     // [2][1024][256] bf16
    unsigned short* hdA, unsigned short* hdB,
    float* __restrict__ documents,
    unsigned* bars)
{
    const int tid  = threadIdx.x;
    const int lane = tid & 63;
    const int w    = tid >> 6;
    const int n    = lane & 15;
    const int quad = lane >> 4;
    const int phys = blockIdx.x;        // 0..15
    const int g    = phys & 7;          // 0..7
    const int p    = (phys >> 3) & 1;
    const int r0   = g * 16;
    const bool bwd = (r0 >= 64);
    unsigned* cnt = bars + g * 16;
    const unsigned short* Wd = WhhBf + (bwd ? (size_t)262144 : 0);

    __shared__ unsigned short Hs[2][16][264];
    __shared__ float G[16][516];

    bf16x8 Bf[4][8];
#pragma unroll
    for (int ct = 0; ct < 4; ct++) {
        const int c    = ct * 16 + n;
        const int unit = p * 128 + w * 16 + (c >> 2);
        const int wrow = (c & 3) * 256 + unit;
        const unsigned short* wr = Wd + (size_t)wrow * 256;
#pragma unroll
        for (int ks = 0; ks < 8; ks++)
            Bf[ct][ks] = *(const bf16x8*)(wr + ks * 32 + quad * 8);
    }

    for (int i = tid; i < 16 * 264; i += 512) ((unsigned short*)Hs[0])[i] = 0;

    const int rE  = tid & 15;
    const int iE  = tid >> 4;
    const int ug4 = p * 128 + iE * 4;
    const int grow_e = r0 + rE;
    const int seq = bwd ? grow_e - 64 : grow_e;     // doc index
    float cr[4] = {0.f, 0.f, 0.f, 0.f};

    const float* xptr = (!bwd ? xw + (size_t)seq * 10 * 2048
                              : xw + ((size_t)seq * 10 + 9) * 2048 + 1024)
                        + (size_t)ug4 * 4;
    const long long xstep = bwd ? -2048 : 2048;
    float4 xv[4];
    { const float4* xp = (const float4*)xptr;
      xv[0] = xp[0]; xv[1] = xp[1]; xv[2] = xp[2]; xv[3] = xp[3]; }

    float* dptr = documents + (size_t)(seq * 10 + (bwd ? 9 : 0)) * 512
                  + (bwd ? 256 : 0) + ug4;
    const long long dstep = bwd ? -512 : 512;

    __syncthreads();

    for (int t = 0; t < 10; t++) {
        const int cur = t & 1;
        unsigned short* hq = (t & 1) ? hdA : hdB;

        {
            bf16x8 Af[8];
#pragma unroll
            for (int ks = 0; ks < 8; ks++)
                Af[ks] = *(const bf16x8*)&Hs[cur][n][ks * 32 + quad * 8];
            f32x4 acc[4];
#pragma unroll
            for (int ct = 0; ct < 4; ct++) acc[ct] = (f32x4){0.f, 0.f, 0.f, 0.f};
#pragma unroll
            for (int ks = 0; ks < 8; ks++)
#pragma unroll
                for (int ct = 0; ct < 4; ct++)
                    acc[ct] = __builtin_amdgcn_mfma_f32_16x16x32_bf16(
                        Af[ks], Bf[ct][ks], acc[ct], 0, 0, 0);
#pragma unroll
            for (int ct = 0; ct < 4; ct++)
#pragma unroll
                for (int r = 0; r < 4; r++)
                    G[quad * 4 + r][w * 64 + ct * 16 + n] = acc[ct][r];
        }
        __syncthreads();

        {
            const float4* Gp = (const float4*)&G[rE][iE * 16];
            unsigned long long hpack = 0ull;
            float hout[4];
#pragma unroll
            for (int q2 = 0; q2 < 4; q2++) {
                float4 gv = Gp[q2];
                float gi = gv.x + xv[q2].x;
                float gf = gv.y + xv[q2].y;
                float gg = gv.z + xv[q2].z;
                float go = gv.w + xv[q2].w;
                float cn = sigm(gf) * cr[q2] + sigm(gi) * ftanh(gg);
                float hn = sigm(go) * ftanh(cn);
                cr[q2] = cn; hout[q2] = hn;
                hpack |= ((unsigned long long)f2bf(hn)) << (16 * q2);
            }
            const int nxt = cur ^ 1;
            *(unsigned long long*)&Hs[nxt][rE][ug4] = hpack;
            __hip_atomic_store((unsigned long long*)(hq + (size_t)grow_e * 256 + ug4),
                               hpack, __ATOMIC_RELAXED, __HIP_MEMORY_SCOPE_AGENT);
            *(float4*)dptr = *(float4*)hout;
        }

        if (t < 9) {
            xptr += xstep;  dptr += dstep;
            const float4* xp = (const float4*)xptr;
            xv[0] = xp[0]; xv[1] = xp[1]; xv[2] = xp[2]; xv[3] = xp[3];
            pair_sync(cnt, 2u * (unsigned)(t + 1));
            {
                const int nxt   = cur ^ 1;
                const int row   = tid >> 5;
                const int chunk = tid & 31;
                const int pp    = p ^ 1;
                unsigned long long v = __hip_atomic_load(
                    (const unsigned long long*)(hq + (size_t)(r0 + row) * 256
                                                + pp * 128 + chunk * 4),
                    __ATOMIC_RELAXED, __HIP_MEMORY_SCOPE_AGENT);
                *(unsigned long long*)&Hs[nxt][row][pp * 128 + chunk * 4] = v;
            }
            __syncthreads();
        }
    }
}

// SourceBias: biasedBf[t] = bf16(tanh(sen[t] @ trans[u] + sb_bias[u]))
__global__ __launch_bounds__(256) void source_bias(
    const float* __restrict__ sentences, const int* __restrict__ urls,
    const float* __restrict__ trans, const float* __restrict__ sb_bias,
    unsigned* __restrict__ biasedBf)
{
    const int tkn = blockIdx.x;
    const int u = urls[tkn];
    const float2* Tm = (const float2*)(trans + (size_t)u * 512 * 512);
    __shared__ float sv[512];
    for (int i = threadIdx.x; i < 512; i += 256) sv[i] = sentences[(size_t)tkn * 512 + i];
    __syncthreads();
    const int e = threadIdx.x;
    float ax = 0.f, ay = 0.f;
#pragma unroll 4
    for (int d = 0; d < 512; d++) {
        float s = sv[d];
        float2 tv = Tm[(size_t)d * 256 + e];
        ax += s * tv.x; ay += s * tv.y;
    }
    const float2 bv = ((const float2*)(sb_bias + (size_t)u * 512))[e];
    float x = ftanh(ax + bv.x), y = ftanh(ay + bv.y);
    biasedBf[(size_t)tkn * 256 + e] = (unsigned)f2bf(x) | ((unsigned)f2bf(y) << 16);
}

// v[b,d] = sum_e attn_W[d,e] * heading[b,e]; block per b
__global__ __launch_bounds__(256) void attn_v(
    const float* __restrict__ W, const float* __restrict__ headings,
    float* __restrict__ v)
{
    const int b = blockIdx.x;
    __shared__ float hh[512];
    for (int i = threadIdx.x; i < 512; i += 256) hh[i] = headings[(size_t)b * 512 + i];
    __syncthreads();
    for (int d = threadIdx.x; d < 512; d += 256) {
        float a = 0.f;
        const float* wr = W + (size_t)d * 512;
        for (int e = 0; e < 512; e++) a += wr[e] * hh[e];
        v[(size_t)b * 512 + d] = a;
    }
}

// scores -> softmax -> doc_rep -> both MLP heads; block per batch element
__global__ __launch_bounds__(256) void attn_heads(
    const float* __restrict__ documents, const float* __restrict__ v,
    const float* __restrict__ attn_b,
    const float* __restrict__ bW1, const float* __restrict__ bb1,
    const float* __restrict__ bW2, const float* __restrict__ bb2,
    const float* __restrict__ tW1, const float* __restrict__ tb1,
    const float* __restrict__ tW2, const float* __restrict__ tb2,
    float* __restrict__ out)
{
    const int b = blockIdx.x, tid = threadIdx.x;
    const int lane = tid & 63, wv_ = tid >> 6;
    __shared__ float vv[512], dr[512], h1s[256], t1s[256], sw[12], lg[5];
    for (int i = tid; i < 512; i += 256) vv[i] = v[(size_t)b * 512 + i];
    __syncthreads();
    for (int q = 0; q < 3; q++) {
        int s = q * 4 + wv_;
        float p = 0.f;
        if (s < 10) {
            const float* dp = documents + (size_t)(b * 10 + s) * 512;
            for (int d = lane; d < 512; d += 64) p += dp[d] * vv[d];
        }
#pragma unroll
        for (int off = 32; off > 0; off >>= 1) p += __shfl_down(p, off, 64);
        if (s < 10 && lane == 0) sw[s] = p + attn_b[0];
    }
    __syncthreads();
    if (tid == 0) {
        float mx = sw[0];
        for (int s = 1; s < 10; s++) mx = fmaxf(mx, sw[s]);
        float sum = 0.f;
        for (int s = 0; s < 10; s++) { sw[s] = __expf(sw[s] - mx); sum += sw[s]; }
        for (int s = 0; s < 10; s++) sw[s] /= sum;
    }
    __syncthreads();
    for (int d = tid; d < 512; d += 256) {
        float a = 0.f;
#pragma unroll
        for (int s = 0; s < 10; s++) a += sw[s] * documents[(size_t)(b * 10 + s) * 512 + d];
        dr[d] = a;
    }
    __syncthreads();
    {
        float a = bb1[tid], a2 = tb1[tid];
        const float* w1 = bW1 + (size_t)tid * 512;
        const float* w2 = tW1 + (size_t)tid * 512;
        for (int k = 0; k < 512; k++) { float x = dr[k]; a += x * w1[k]; a2 += x * w2[k]; }
        h1s[tid] = ftanh(a); t1s[tid] = ftanh(a2);
    }
    __syncthreads();
    if (tid < 5) {
        float a = bb2[tid];
        const float* wp = bW2 + (size_t)tid * 256;
        for (int k = 0; k < 256; k++) a += h1s[k] * wp[k];
        lg[tid] = ftanh(a);
    }
    if (tid == 32) {
        float a = tb2[0];
        for (int k = 0; k < 256; k++) a += t1s[k] * tW2[k];
        out[320 + b] = sigm(ftanh(a));
    }
    __syncthreads();
    if (tid == 0) {
        float mx = lg[0];
        for (int j = 1; j < 5; j++) mx = fmaxf(mx, lg[j]);
        float sum = 0.f, e[5];
        for (int j = 0; j < 5; j++) { e[j] = __expf(lg[j] - mx); sum += e[j]; }
        for (int j = 0; j < 5; j++) out[b * 5 + j] = e[j] / sum;
    }
}

extern "C" void kernel_launch(void* const* d_in, const int* in_sizes, int n_in,
                              void* d_out, int out_size, void* d_ws, size_t ws_size,
                              hipStream_t stream)
{
    (void)in_sizes; (void)n_in; (void)out_size; (void)ws_size;
    const int*   input_ids = (const int*)d_in[0];
    const int*   urls      = (const int*)d_in[1];
    const int*   titles    = (const int*)d_in[2];
    const float* emb       = (const float*)d_in[3];
    const float* sen_wih_f = (const float*)d_in[4];
    const float* sen_whh_f = (const float*)d_in[5];
    const float* sen_b_f   = (const float*)d_in[6];
    const float* sen_wih_b = (const float*)d_in[7];
    const float* sen_whh_b = (const float*)d_in[8];
    const float* sen_b_b   = (const float*)d_in[9];
    const float* trans     = (const float*)d_in[10];
    const float* sb_bias   = (const float*)d_in[11];
    const float* doc_wih_f = (const float*)d_in[12];
    const float* doc_whh_f = (const float*)d_in[13];
    const float* doc_b_f   = (const float*)d_in[14];
    const float* doc_wih_b = (const float*)d_in[15];
    const float* doc_whh_b = (const float*)d_in[16];
    const float* doc_b_b   = (const float*)d_in[17];
    const float* attn_W    = (const float*)d_in[18];
    const float* attn_b    = (const float*)d_in[19];
    const float* bias_W1   = (const float*)d_in[20];
    const float* bias_b1   = (const float*)d_in[21];
    const float* bias_W2   = (const float*)d_in[22];
    const float* bias_b2   = (const float*)d_in[23];
    const float* truth_W1  = (const float*)d_in[24];
    const float* truth_b1  = (const float*)d_in[25];
    const float* truth_W2  = (const float*)d_in[26];
    const float* truth_b2  = (const float*)d_in[27];
    float* out = (float*)d_out;

    float* ws = (float*)d_ws;
    float* xw_all      = ws;
    float* xw_head     = xw_all + (size_t)19200 * 2048;
    unsigned* biasedBf = (unsigned*)(ws + 0);
    float* xw_doc      = ws + 163840;
    float* documents   = ws + 1474560;
    float* vbuf        = ws + 1802240;

    float* slotB       = ws + 41287680;
    unsigned* Abf      = (unsigned*)slotB;
    float* sentences   = slotB;
    float* headings    = slotB + 327680;
    unsigned* WhhSbf   = (unsigned*)(slotB + 360448);   // [2][1024][128] u32
    unsigned* WhhDbf   = (unsigned*)(slotB + 622592);
    unsigned short* hbA = (unsigned short*)(slotB + 884736);
    unsigned short* hbB = (unsigned short*)(slotB + 1064960);
    unsigned short* hdA = (unsigned short*)(slotB + 1245184);
    unsigned short* hdB = (unsigned short*)(slotB + 1261568);
    unsigned* barsS    = (unsigned*)(slotB + 1277952);  // 88 pair counters
    unsigned* barsD    = barsS + 88 * 16;               // 8 pair counters

    unsigned* Wsen     = (unsigned*)(ws + 44513280);
    unsigned* Wdoc     = (unsigned*)(ws + 44840960);

    dim3 blk(256);

    // D1: gather + bf16 casts
    prep_cast<<<dim3((N0 + N1 + N2 + 255) / 256), blk, 0, stream>>>(
        input_ids, titles, emb, sen_wih_f, sen_wih_b, doc_wih_f, doc_wih_b,
        Abf, Wsen, Wdoc);

    // D2: sentence+title input projection
    proj_mfma<<<dim3(158, 16), blk, 0, stream>>>(
        (const unsigned short*)Abf, 20160, 320,
        (const unsigned short*)Wsen, sen_b_f, sen_b_b, xw_all);

    // bars zero + Whh bf16 cast (slot B dead after D2)
    hipMemsetAsync(barsS, 0, (88 + 8) * 16 * sizeof(unsigned), stream);
    prep_whh<<<dim3(2048), blk, 0, stream>>>(
        sen_whh_f, sen_whh_b, doc_whh_f, doc_whh_b, WhhSbf, WhhDbf);

    // D3: persistent sentence/heading BiLSTM
    lstm_sen2b<<<dim3(176), dim3(512), 0, stream>>>(
        xw_all, xw_head, (const unsigned short*)WhhSbf, hbA, hbB,
        sentences, headings, barsS);

    // D4: SourceBias
    source_bias<<<dim3(640), blk, 0, stream>>>(sentences, urls, trans, sb_bias, biasedBf);

    // D5: document input projection
    proj_mfma<<<dim3(5, 16), blk, 0, stream>>>(
        (const unsigned short*)biasedBf, 640, 512,
        (const unsigned short*)Wdoc, doc_b_f, doc_b_b, xw_doc);

    // D6: persistent document BiLSTM
    lstm_doc2b<<<dim3(16), dim3(512), 0, stream>>>(
        xw_doc, (const unsigned short*)WhhDbf, hdA, hdB, documents, barsD);

    // D7/D8: attention + heads
    attn_v<<<dim3(64), blk, 0, stream>>>(attn_W, headings, vbuf);
    attn_heads<<<dim3(64), blk, 0, stream>>>(documents, vbuf, attn_b,
                                             bias_W1, bias_b1, bias_W2, bias_b2,
                                             truth_W1, truth_b1, truth_W2, truth_b2,
                                             out);
}

// Round 8
// 529.410 us; speedup vs baseline: 9.8285x; 1.0634x over previous
//
#include <hip/hip_runtime.h>
#include <cstddef>

typedef short bf16x8 __attribute__((ext_vector_type(8)));
typedef float f32x4 __attribute__((ext_vector_type(4)));

// fast sigmoid/tanh via v_exp_f32 + v_rcp_f32 (~1e-7 abs err; validated R4-R7:
// absmax identical to libm build)
__device__ __forceinline__ float sigm(float x) {
    return __builtin_amdgcn_rcpf(1.f + __expf(-x));
}
__device__ __forceinline__ float ftanh(float x) {
    float e = __expf(2.f * x);
    return 1.f - 2.f * __builtin_amdgcn_rcpf(e + 1.f);
}

// f32 -> bf16 (round to nearest even)
__device__ __forceinline__ unsigned short f2bf(float f) {
    union { float f; unsigned u; } v; v.f = f;
    return (unsigned short)((v.u + 0x7FFFu + ((v.u >> 16) & 1u)) >> 16);
}

// ============================================================================
// prep_cast: one pass producing all bf16 operands.
// ============================================================================
#define N0 (20160 * 160)
#define N1 (2048 * 160)
#define N2 (2048 * 256)

__global__ __launch_bounds__(256) void prep_cast(
    const int* __restrict__ ids, const int* __restrict__ titles,
    const float* __restrict__ emb,
    const float* __restrict__ swf, const float* __restrict__ swb,
    const float* __restrict__ dwf, const float* __restrict__ dwb,
    unsigned* __restrict__ Abf, unsigned* __restrict__ Wsen,
    unsigned* __restrict__ Wdoc)
{
    int idx = blockIdx.x * 256 + threadIdx.x;
    if (idx < N0) {
        int row = idx / 160, kk = idx - row * 160;
        int id = (row < 19200) ? ids[row] : titles[row - 19200];
        float a = 0.f, b = 0.f;
        if (kk < 150) {
            const float* s = emb + (size_t)id * 300 + kk * 2;
            a = s[0]; b = s[1];
        }
        Abf[idx] = (unsigned)f2bf(a) | ((unsigned)f2bf(b) << 16);
    } else if (idx < N0 + N1) {
        int j = idx - N0;
        int row = j / 160, kk = j - row * 160;
        const float* base = (row < 1024) ? swf + (size_t)row * 300
                                         : swb + (size_t)(row - 1024) * 300;
        float a = 0.f, b = 0.f;
        if (kk < 150) { a = base[kk * 2]; b = base[kk * 2 + 1]; }
        Wsen[j] = (unsigned)f2bf(a) | ((unsigned)f2bf(b) << 16);
    } else if (idx < N0 + N1 + N2) {
        int j = idx - N0 - N1;
        int row = j >> 8, kk = j & 255;
        const float* base = (row < 1024) ? dwf + (size_t)row * 512
                                         : dwb + (size_t)(row - 1024) * 512;
        Wdoc[j] = (unsigned)f2bf(base[kk * 2]) | ((unsigned)f2bf(base[kk * 2 + 1]) << 16);
    }
}

// ============================================================================
// prep_whh: cast LSTM hidden weights to bf16, row-major [dir][1024][256].
// ============================================================================
__global__ __launch_bounds__(256) void prep_whh(
    const float* __restrict__ swf, const float* __restrict__ swb,
    const float* __restrict__ dwf, const float* __restrict__ dwb,
    unsigned* __restrict__ WS, unsigned* __restrict__ WD)
{
    int idx = blockIdx.x * 256 + threadIdx.x;   // 0 .. 524287
    const float* src; unsigned* dst;
    if (idx < 262144) {
        int j = idx; int dir = j >> 17; int rem = j & 131071;
        src = (dir ? swb : swf) + ((size_t)(rem >> 7) * 256 + (rem & 127) * 2);
        dst = WS + j;
    } else {
        int j = idx - 262144; int dir = j >> 17; int rem = j & 131071;
        src = (dir ? dwb : dwf) + ((size_t)(rem >> 7) * 256 + (rem & 127) * 2);
        dst = WD + j;
    }
    *dst = (unsigned)f2bf(src[0]) | ((unsigned)f2bf(src[1]) << 16);
}

// ============================================================================
// proj_mfma: out[M][2048] = Abf[M][Kp] @ Wbf^T + bias, output GATE-INTERLEAVED:
//   col = half*1024 + unit*4 + gate
// ============================================================================
__global__ __launch_bounds__(256) void proj_mfma(
    const unsigned short* __restrict__ Abf, int M, int Kp,
    const unsigned short* __restrict__ Wbf,
    const float* __restrict__ bf_, const float* __restrict__ bb_,
    float* __restrict__ out)
{
    __shared__ unsigned short As[128 * 40];   // pitch 80B (16B aligned)
    __shared__ unsigned short Ws[128 * 40];
    const int tid  = threadIdx.x;
    const int lane = tid & 63;
    const int w    = tid >> 6;
    const int n    = lane & 15;
    const int quad = lane >> 4;
    const int bm   = blockIdx.x * 128;
    const int by   = blockIdx.y;              // 0..15
    const int half = by >> 3;
    const int ug32 = (by & 7) * 32;
    const unsigned short* Wb = Wbf + (size_t)half * 1024 * Kp;
    const float* biasp = half ? bb_ : bf_;

    f32x4 acc[2][8];
#pragma unroll
    for (int rt = 0; rt < 2; rt++)
#pragma unroll
        for (int ct = 0; ct < 8; ct++) acc[rt][ct] = (f32x4){0.f, 0.f, 0.f, 0.f};

    const int chunks = Kp >> 5;
    for (int kc = 0; kc < chunks; kc++) {
        const int k0 = kc * 32;
#pragma unroll
        for (int j = 0; j < 2; j++) {
            int idx = j * 256 + tid;
            int arow = idx >> 2, qq = idx & 3;
            int grow = bm + arow; if (grow >= M) grow = M - 1;
            *(uint4*)&As[arow * 40 + qq * 8] =
                *(const uint4*)(Abf + (size_t)grow * Kp + k0 + qq * 8);
            int cc = idx >> 2;
            int wrow = (cc >> 5) * 256 + ug32 + (cc & 31);
            *(uint4*)&Ws[cc * 40 + qq * 8] =
                *(const uint4*)(Wb + (size_t)wrow * Kp + k0 + qq * 8);
        }
        __syncthreads();
        bf16x8 Aq[2], Bq[8];
#pragma unroll
        for (int rt = 0; rt < 2; rt++)
            Aq[rt] = *(const bf16x8*)&As[((w * 2 + rt) * 16 + n) * 40 + quad * 8];
#pragma unroll
        for (int ct = 0; ct < 8; ct++)
            Bq[ct] = *(const bf16x8*)&Ws[(ct * 16 + n) * 40 + quad * 8];
#pragma unroll
        for (int rt = 0; rt < 2; rt++)
#pragma unroll
            for (int ct = 0; ct < 8; ct++)
                acc[rt][ct] = __builtin_amdgcn_mfma_f32_16x16x32_bf16(
                    Aq[rt], Bq[ct], acc[rt][ct], 0, 0, 0);
        __syncthreads();
    }

#pragma unroll
    for (int s = 0; s < 2; s++) {
        const int uL = s * 16 + n;
        float b0 = biasp[ug32 + uL];
        float b1 = biasp[256 + ug32 + uL];
        float b2 = biasp[512 + ug32 + uL];
        float b3 = biasp[768 + ug32 + uL];
#pragma unroll
        for (int rt = 0; rt < 2; rt++) {
#pragma unroll
            for (int r = 0; r < 4; r++) {
                int row = bm + (w * 2 + rt) * 16 + quad * 4 + r;
                if (row >= M) continue;
                float4 o;
                o.x = acc[rt][0 + s][r] + b0;
                o.y = acc[rt][2 + s][r] + b1;
                o.z = acc[rt][4 + s][r] + b2;
                o.w = acc[rt][6 + s][r] + b3;
                *(float4*)(out + (size_t)row * 2048 + half * 1024 + (ug32 + uL) * 4) = o;
            }
        }
    }
}

// ---------------------------------------------------------------------------
// pair_sync (R3-proven): 2 blocks, MONOTONIC counter, relaxed agent atomics,
// thread0 increments + throttled poll. __syncthreads drains h-stores (vmcnt)
// before arrival.
// ---------------------------------------------------------------------------
__device__ __forceinline__ void pair_sync(unsigned* cnt, unsigned target) {
    __syncthreads();
    if (threadIdx.x == 0) {
        __hip_atomic_fetch_add(cnt, 1u, __ATOMIC_RELAXED, __HIP_MEMORY_SCOPE_AGENT);
        while (__hip_atomic_load(cnt, __ATOMIC_RELAXED, __HIP_MEMORY_SCOPE_AGENT) < target)
            __builtin_amdgcn_s_sleep(1);
    }
    __syncthreads();
}

__device__ __forceinline__ const float* sen_xbase(
    const float* xw, const float* xw_head, int grow_e, int t)
{
    if (grow_e < 640)       return xw + ((size_t)grow_e * 30 + t) * 2048;
    else if (grow_e < 1280) return xw + ((size_t)(grow_e - 640) * 30 + 29 - t) * 2048 + 1024;
    else if (grow_e < 1344) return xw_head + ((size_t)(grow_e - 1280) * 15 + t) * 2048;
    else                    return xw_head + ((size_t)(grow_e - 1344) * 15 + 14 - t) * 2048 + 1024;
}

// ============================================================================
// lstm_sen2b: VERIFIED R7 kernel (102.9 us) — unchanged.
// ============================================================================
__global__ __launch_bounds__(512, 2) void lstm_sen2b(
    const float* __restrict__ xw, const float* __restrict__ xw_head,
    const unsigned short* __restrict__ WhhBf,     // [2][1024][256] bf16
    unsigned short* hbA, unsigned short* hbB,
    float* __restrict__ sentences, float* __restrict__ headings,
    unsigned* bars)
{
    const int tid  = threadIdx.x;
    const int lane = tid & 63;
    const int w    = tid >> 6;          // 0..7 (wave)
    const int n    = lane & 15;
    const int quad = lane >> 4;
    const int phys = blockIdx.x;        // 0..175
    const int g    = (phys & 7) + (phys >> 4) * 8;   // 0..87 (pair group)
    const int p    = (phys >> 3) & 1;                // unit-half
    const int r0   = g * 16;
    const bool bwd  = (r0 >= 640 && r0 < 1280) || (r0 >= 1344);
    const bool head = (r0 >= 1280);
    const int tEnd = head ? 15 : 30;
    unsigned* cnt = bars + g * 16;      // 64B-separated counters
    const unsigned short* Wd = WhhBf + (bwd ? (size_t)262144 : 0);

    __shared__ unsigned short Hs[2][16][264];   // pitch 528B
    __shared__ float G[16][516];                // pitch 2064B

    // B fragments: wave w owns local cols w*64 + ct*16 + n
    bf16x8 Bf[4][8];
#pragma unroll
    for (int ct = 0; ct < 4; ct++) {
        const int c    = ct * 16 + n;
        const int unit = p * 128 + w * 16 + (c >> 2);
        const int wrow = (c & 3) * 256 + unit;
        const unsigned short* wr = Wd + (size_t)wrow * 256;
#pragma unroll
        for (int ks = 0; ks < 8; ks++)
            Bf[ct][ks] = *(const bf16x8*)(wr + ks * 32 + quad * 8);
    }

    // zero h(t=0)
    for (int i = tid; i < 16 * 264; i += 512) ((unsigned short*)Hs[0])[i] = 0;

    const int rE  = tid & 15;            // row within group
    const int iE  = tid >> 4;            // 0..31
    const int ug4 = p * 128 + iE * 4;    // global unit base (4 units/thread)
    const int grow_e = r0 + rE;
    float cr[4] = {0.f, 0.f, 0.f, 0.f};

    // pointer-stepped xw prefetch
    const float* xptr = sen_xbase(xw, xw_head, grow_e, 0) + (size_t)ug4 * 4;
    const long long xstep = bwd ? -2048 : 2048;
    float4 xv[4];
    { const float4* xp = (const float4*)xptr;
      xv[0] = xp[0]; xv[1] = xp[1]; xv[2] = xp[2]; xv[3] = xp[3]; }

    // final h destination
    float* fdst;
    if (!head) fdst = sentences + (size_t)(bwd ? grow_e - 640 : grow_e) * 512
                      + (bwd ? 256 : 0) + ug4;
    else       fdst = headings + (size_t)(grow_e - (bwd ? 1344 : 1280)) * 512
                      + (bwd ? 256 : 0) + ug4;

    __syncthreads();

    for (int t = 0; t < tEnd; t++) {
        const int cur = t & 1;
        unsigned short* hq = (t & 1) ? hbA : hbB;

        // ---- hidden GEMM: G[0..15][own 512 cols] = h(t) @ Whh-half ----
        {
            bf16x8 Af[8];
#pragma unroll
            for (int ks = 0; ks < 8; ks++)
                Af[ks] = *(const bf16x8*)&Hs[cur][n][ks * 32 + quad * 8];
            f32x4 acc[4];
#pragma unroll
            for (int ct = 0; ct < 4; ct++) acc[ct] = (f32x4){0.f, 0.f, 0.f, 0.f};
#pragma unroll
            for (int ks = 0; ks < 8; ks++)
#pragma unroll
                for (int ct = 0; ct < 4; ct++)
                    acc[ct] = __builtin_amdgcn_mfma_f32_16x16x32_bf16(
                        Af[ks], Bf[ct][ks], acc[ct], 0, 0, 0);
#pragma unroll
            for (int ct = 0; ct < 4; ct++)
#pragma unroll
                for (int r = 0; r < 4; r++)
                    G[quad * 4 + r][w * 64 + ct * 16 + n] = acc[ct][r];
        }
        __syncthreads();

        // ---- gate epilogue: 4 (row,unit) pairs per thread ----
        {
            const float4* Gp = (const float4*)&G[rE][iE * 16];
            unsigned long long hpack = 0ull;
            float hout[4];
#pragma unroll
            for (int q2 = 0; q2 < 4; q2++) {
                float4 gv = Gp[q2];
                float gi = gv.x + xv[q2].x;
                float gf = gv.y + xv[q2].y;
                float gg = gv.z + xv[q2].z;
                float go = gv.w + xv[q2].w;
                float cn = sigm(gf) * cr[q2] + sigm(gi) * ftanh(gg);
                float hn = sigm(go) * ftanh(cn);
                cr[q2] = cn; hout[q2] = hn;
                hpack |= ((unsigned long long)f2bf(hn)) << (16 * q2);
            }
            const int nxt = cur ^ 1;
            *(unsigned long long*)&Hs[nxt][rE][ug4] = hpack;   // own half -> LDS
            __hip_atomic_store((unsigned long long*)(hq + (size_t)grow_e * 256 + ug4),
                               hpack, __ATOMIC_RELAXED, __HIP_MEMORY_SCOPE_AGENT);
            if (t == tEnd - 1) *(float4*)fdst = *(float4*)hout;
        }

        if (t + 1 < tEnd) {
            // prefetch next step's xw BEFORE the sync wait (h-independent)
            xptr += xstep;
            const float4* xp = (const float4*)xptr;
            xv[0] = xp[0]; xv[1] = xp[1]; xv[2] = xp[2]; xv[3] = xp[3];
            pair_sync(cnt, 2u * (unsigned)(t + 1));
            // partner half -> Hs[nxt]: one 8B chunk per thread (16 rows x 32)
            {
                const int nxt   = cur ^ 1;
                const int row   = tid >> 5;
                const int chunk = tid & 31;
                const int pp    = p ^ 1;
                unsigned long long v = __hip_atomic_load(
                    (const unsigned long long*)(hq + (size_t)(r0 + row) * 256
                                                + pp * 128 + chunk * 4),
                    __ATOMIC_RELAXED, __HIP_MEMORY_SCOPE_AGENT);
                *(unsigned long long*)&Hs[nxt][row][pp * 128 + chunk * 4] = v;
            }
            __syncthreads();
        }
    }
}

// ============================================================================
// lstm_doc2b: VERIFIED R7 kernel — unchanged.
// ============================================================================
__global__ __launch_bounds__(512, 2) void lstm_doc2b(
    const float* __restrict__ xw,
    const unsigned short* __restrict__ WhhBf,     // [2][1024][256] bf16
    unsigned short* hdA, unsigned short* hdB,
    float* __restrict__ documents,
    unsigned* bars)
{
    const int tid  = threadIdx.x;
    const int lane = tid & 63;
    const int w    = tid >> 6;
    const int n    = lane & 15;
    const int quad = lane >> 4;
    const int phys = blockIdx.x;        // 0..15
    const int g    = phys & 7;          // 0..7
    const int p    = (phys >> 3) & 1;
    const int r0   = g * 16;
    const bool bwd = (r0 >= 64);
    unsigned* cnt = bars + g * 16;
    const unsigned short* Wd = WhhBf + (bwd ? (size_t)262144 : 0);

    __shared__ unsigned short Hs[2][16][264];
    __shared__ float G[16][516];

    bf16x8 Bf[4][8];
#pragma unroll
    for (int ct = 0; ct < 4; ct++) {
        const int c    = ct * 16 + n;
        const int unit = p * 128 + w * 16 + (c >> 2);
        const int wrow = (c & 3) * 256 + unit;
        const unsigned short* wr = Wd + (size_t)wrow * 256;
#pragma unroll
        for (int ks = 0; ks < 8; ks++)
            Bf[ct][ks] = *(const bf16x8*)(wr + ks * 32 + quad * 8);
    }

    for (int i = tid; i < 16 * 264; i += 512) ((unsigned short*)Hs[0])[i] = 0;

    const int rE  = tid & 15;
    const int iE  = tid >> 4;
    const int ug4 = p * 128 + iE * 4;
    const int grow_e = r0 + rE;
    const int seq = bwd ? grow_e - 64 : grow_e;     // doc index
    float cr[4] = {0.f, 0.f, 0.f, 0.f};

    const float* xptr = (!bwd ? xw + (size_t)seq * 10 * 2048
                              : xw + ((size_t)seq * 10 + 9) * 2048 + 1024)
                        + (size_t)ug4 * 4;
    const long long xstep = bwd ? -2048 : 2048;
    float4 xv[4];
    { const float4* xp = (const float4*)xptr;
      xv[0] = xp[0]; xv[1] = xp[1]; xv[2] = xp[2]; xv[3] = xp[3]; }

    float* dptr = documents + (size_t)(seq * 10 + (bwd ? 9 : 0)) * 512
                  + (bwd ? 256 : 0) + ug4;
    const long long dstep = bwd ? -512 : 512;

    __syncthreads();

    for (int t = 0; t < 10; t++) {
        const int cur = t & 1;
        unsigned short* hq = (t & 1) ? hdA : hdB;

        {
            bf16x8 Af[8];
#pragma unroll
            for (int ks = 0; ks < 8; ks++)
                Af[ks] = *(const bf16x8*)&Hs[cur][n][ks * 32 + quad * 8];
            f32x4 acc[4];
#pragma unroll
            for (int ct = 0; ct < 4; ct++) acc[ct] = (f32x4){0.f, 0.f, 0.f, 0.f};
#pragma unroll
            for (int ks = 0; ks < 8; ks++)
#pragma unroll
                for (int ct = 0; ct < 4; ct++)
                    acc[ct] = __builtin_amdgcn_mfma_f32_16x16x32_bf16(
                        Af[ks], Bf[ct][ks], acc[ct], 0, 0, 0);
#pragma unroll
            for (int ct = 0; ct < 4; ct++)
#pragma unroll
                for (int r = 0; r < 4; r++)
                    G[quad * 4 + r][w * 64 + ct * 16 + n] = acc[ct][r];
        }
        __syncthreads();

        {
            const float4* Gp = (const float4*)&G[rE][iE * 16];
            unsigned long long hpack = 0ull;
            float hout[4];
#pragma unroll
            for (int q2 = 0; q2 < 4; q2++) {
                float4 gv = Gp[q2];
                float gi = gv.x + xv[q2].x;
                float gf = gv.y + xv[q2].y;
                float gg = gv.z + xv[q2].z;
                float go = gv.w + xv[q2].w;
                float cn = sigm(gf) * cr[q2] + sigm(gi) * ftanh(gg);
                float hn = sigm(go) * ftanh(cn);
                cr[q2] = cn; hout[q2] = hn;
                hpack |= ((unsigned long long)f2bf(hn)) << (16 * q2);
            }
            const int nxt = cur ^ 1;
            *(unsigned long long*)&Hs[nxt][rE][ug4] = hpack;
            __hip_atomic_store((unsigned long long*)(hq + (size_t)grow_e * 256 + ug4),
                               hpack, __ATOMIC_RELAXED, __HIP_MEMORY_SCOPE_AGENT);
            *(float4*)dptr = *(float4*)hout;
        }

        if (t < 9) {
            xptr += xstep;  dptr += dstep;
            const float4* xp = (const float4*)xptr;
            xv[0] = xp[0]; xv[1] = xp[1]; xv[2] = xp[2]; xv[3] = xp[3];
            pair_sync(cnt, 2u * (unsigned)(t + 1));
            {
                const int nxt   = cur ^ 1;
                const int row   = tid >> 5;
                const int chunk = tid & 31;
                const int pp    = p ^ 1;
                unsigned long long v = __hip_atomic_load(
                    (const unsigned long long*)(hq + (size_t)(r0 + row) * 256
                                                + pp * 128 + chunk * 4),
                    __ATOMIC_RELAXED, __HIP_MEMORY_SCOPE_AGENT);
                *(unsigned long long*)&Hs[nxt][row][pp * 128 + chunk * 4] = v;
            }
            __syncthreads();
        }
    }
}

// ============================================================================
// source_bias_g: URL-GROUPED SourceBias. Grid (64 urls, 8 col-slices), 256 thr.
// Old version: 640 blocks x 1 MB trans reads = 640 MB cache traffic. Here each
// block buckets its url's tokens (LDS atomic append; order irrelevant — each
// token writes its own output row) and streams its 128 KB W-slice ONCE for all
// of them: total trans traffic ~64 MB (one pass). 4 waves stripe d (wave w
// handles d%4==w, coalesced 256B row loads); fp32 accumulate in registers;
// 4-way LDS reduce; tanh+bf16 pack on write.
// ============================================================================
__global__ __launch_bounds__(256) void source_bias_g(
    const float* __restrict__ sentences, const int* __restrict__ urls,
    const float* __restrict__ trans, const float* __restrict__ sb_bias,
    unsigned* __restrict__ biasedBf)
{
    const int u   = blockIdx.x;          // url
    const int s   = blockIdx.y;          // col-slice: cols [s*64, s*64+64)
    const int tid = threadIdx.x;
    __shared__ int   toks[640];
    __shared__ int   cntS;
    __shared__ float sv[16][516];        // 16 tokens x 512 f32 (pitch 2064B)
    __shared__ float red[4][64][17];     // dq x localcol x token (padded)

    if (tid == 0) cntS = 0;
    __syncthreads();
    for (int i = tid; i < 640; i += 256) {
        if (urls[i] == u) {
            int slot = atomicAdd(&cntS, 1);
            toks[slot] = i;
        }
    }
    __syncthreads();
    const int cnt = cntS;
    const int dq  = tid >> 6;            // wave index 0..3 (d-stripe)
    const int eL  = tid & 63;            // local col
    const int e   = s * 64 + eL;
    const float* Tm = trans + (size_t)u * 512 * 512;

    for (int t0 = 0; t0 < cnt; t0 += 16) {
        const int nt = (cnt - t0 < 16) ? (cnt - t0) : 16;
        // stage sentence rows (f32, coalesced float4)
        for (int i = tid; i < 16 * 128; i += 256) {
            int r = i >> 7, c4 = i & 127;
            float4 v4;
            if (r < nt) v4 = *(const float4*)(sentences + (size_t)toks[t0 + r] * 512 + c4 * 4);
            else        v4 = (float4){0.f, 0.f, 0.f, 0.f};
            *(float4*)&sv[r][c4 * 4] = v4;
        }
        __syncthreads();

        float ax[16];
#pragma unroll
        for (int r = 0; r < 16; r++) ax[r] = 0.f;
        for (int it = 0; it < 128; it++) {
            const int d = it * 4 + dq;
            float wv = Tm[(size_t)d * 512 + e];
#pragma unroll
            for (int r = 0; r < 16; r++) ax[r] += sv[r][d] * wv;
        }
#pragma unroll
        for (int r = 0; r < 16; r++) red[dq][eL][r] = ax[r];
        __syncthreads();

        // outputs: nt tokens x 32 u32-pairs for this slice
        for (int o = tid; o < nt * 32; o += 256) {
            int t  = o >> 5, ep = o & 31;
            int c0 = ep * 2, c1 = c0 + 1;
            float x0 = red[0][c0][t] + red[1][c0][t] + red[2][c0][t] + red[3][c0][t];
            float x1 = red[0][c1][t] + red[1][c1][t] + red[2][c1][t] + red[3][c1][t];
            int tkn = toks[t0 + t];
            int eg  = s * 32 + ep;       // u32 index within the 256-wide row
            const float2 bv = ((const float2*)(sb_bias + (size_t)u * 512))[eg];
            float xx = ftanh(x0 + bv.x), yy = ftanh(x1 + bv.y);
            biasedBf[(size_t)tkn * 256 + eg] =
                (unsigned)f2bf(xx) | ((unsigned)f2bf(yy) << 16);
        }
        __syncthreads();                 // sv/red reuse next tile
    }
}

// ============================================================================
// attn_heads (attn_v FUSED): scores -> softmax -> doc_rep -> both MLP heads.
// Block per batch element; computes its own v = attn_W @ heading (W re-reads
// are L2-resident across the 64 blocks).
// ============================================================================
__global__ __launch_bounds__(256) void attn_heads(
    const float* __restrict__ documents, const float* __restrict__ W,
    const float* __restrict__ headings,
    const float* __restrict__ attn_b,
    const float* __restrict__ bW1, const float* __restrict__ bb1,
    const float* __restrict__ bW2, const float* __restrict__ bb2,
    const float* __restrict__ tW1, const float* __restrict__ tb1,
    const float* __restrict__ tW2, const float* __restrict__ tb2,
    float* __restrict__ out)
{
    const int b = blockIdx.x, tid = threadIdx.x;
    const int lane = tid & 63, wv_ = tid >> 6;
    __shared__ float hh[512], vv[512], dr[512], h1s[256], t1s[256], sw[12], lg[5];
    for (int i = tid; i < 512; i += 256) hh[i] = headings[(size_t)b * 512 + i];
    __syncthreads();
    // v[d] = sum_e W[d][e] * hh[e]
    for (int d = tid; d < 512; d += 256) {
        float a = 0.f;
        const float* wr = W + (size_t)d * 512;
        for (int e2 = 0; e2 < 512; e2++) a += wr[e2] * hh[e2];
        vv[d] = a;
    }
    __syncthreads();
    for (int q = 0; q < 3; q++) {
        int s = q * 4 + wv_;
        float p = 0.f;
        if (s < 10) {
            const float* dp = documents + (size_t)(b * 10 + s) * 512;
            for (int d = lane; d < 512; d += 64) p += dp[d] * vv[d];
        }
#pragma unroll
        for (int off = 32; off > 0; off >>= 1) p += __shfl_down(p, off, 64);
        if (s < 10 && lane == 0) sw[s] = p + attn_b[0];
    }
    __syncthreads();
    if (tid == 0) {
        float mx = sw[0];
        for (int s = 1; s < 10; s++) mx = fmaxf(mx, sw[s]);
        float sum = 0.f;
        for (int s = 0; s < 10; s++) { sw[s] = __expf(sw[s] - mx); sum += sw[s]; }
        for (int s = 0; s < 10; s++) sw[s] /= sum;
    }
    __syncthreads();
    for (int d = tid; d < 512; d += 256) {
        float a = 0.f;
#pragma unroll
        for (int s = 0; s < 10; s++) a += sw[s] * documents[(size_t)(b * 10 + s) * 512 + d];
        dr[d] = a;
    }
    __syncthreads();
    {
        float a = bb1[tid], a2 = tb1[tid];
        const float* w1 = bW1 + (size_t)tid * 512;
        const float* w2 = tW1 + (size_t)tid * 512;
        for (int k = 0; k < 512; k++) { float x = dr[k]; a += x * w1[k]; a2 += x * w2[k]; }
        h1s[tid] = ftanh(a); t1s[tid] = ftanh(a2);
    }
    __syncthreads();
    if (tid < 5) {
        float a = bb2[tid];
        const float* wp = bW2 + (size_t)tid * 256;
        for (int k = 0; k < 256; k++) a += h1s[k] * wp[k];
        lg[tid] = ftanh(a);
    }
    if (tid == 32) {
        float a = tb2[0];
        for (int k = 0; k < 256; k++) a += t1s[k] * tW2[k];
        out[320 + b] = sigm(ftanh(a));
    }
    __syncthreads();
    if (tid == 0) {
        float mx = lg[0];
        for (int j = 1; j < 5; j++) mx = fmaxf(mx, lg[j]);
        float sum = 0.f, e[5];
        for (int j = 0; j < 5; j++) { e[j] = __expf(lg[j] - mx); sum += e[j]; }
        for (int j = 0; j < 5; j++) out[b * 5 + j] = e[j] / sum;
    }
}

extern "C" void kernel_launch(void* const* d_in, const int* in_sizes, int n_in,
                              void* d_out, int out_size, void* d_ws, size_t ws_size,
                              hipStream_t stream)
{
    (void)in_sizes; (void)n_in; (void)out_size; (void)ws_size;
    const int*   input_ids = (const int*)d_in[0];
    const int*   urls      = (const int*)d_in[1];
    const int*   titles    = (const int*)d_in[2];
    const float* emb       = (const float*)d_in[3];
    const float* sen_wih_f = (const float*)d_in[4];
    const float* sen_whh_f = (const float*)d_in[5];
    const float* sen_b_f   = (const float*)d_in[6];
    const float* sen_wih_b = (const float*)d_in[7];
    const float* sen_whh_b = (const float*)d_in[8];
    const float* sen_b_b   = (const float*)d_in[9];
    const float* trans     = (const float*)d_in[10];
    const float* sb_bias   = (const float*)d_in[11];
    const float* doc_wih_f = (const float*)d_in[12];
    const float* doc_whh_f = (const float*)d_in[13];
    const float* doc_b_f   = (const float*)d_in[14];
    const float* doc_wih_b = (const float*)d_in[15];
    const float* doc_whh_b = (const float*)d_in[16];
    const float* doc_b_b   = (const float*)d_in[17];
    const float* attn_W    = (const float*)d_in[18];
    const float* attn_b    = (const float*)d_in[19];
    const float* bias_W1   = (const float*)d_in[20];
    const float* bias_b1   = (const float*)d_in[21];
    const float* bias_W2   = (const float*)d_in[22];
    const float* bias_b2   = (const float*)d_in[23];
    const float* truth_W1  = (const float*)d_in[24];
    const float* truth_b1  = (const float*)d_in[25];
    const float* truth_W2  = (const float*)d_in[26];
    const float* truth_b2  = (const float*)d_in[27];
    float* out = (float*)d_out;

    float* ws = (float*)d_ws;
    float* xw_all      = ws;
    float* xw_head     = xw_all + (size_t)19200 * 2048;
    unsigned* biasedBf = (unsigned*)(ws + 0);
    float* xw_doc      = ws + 163840;
    float* documents   = ws + 1474560;

    float* slotB       = ws + 41287680;
    unsigned* Abf      = (unsigned*)slotB;
    float* sentences   = slotB;
    float* headings    = slotB + 327680;
    unsigned* WhhSbf   = (unsigned*)(slotB + 360448);   // [2][1024][128] u32
    unsigned* WhhDbf   = (unsigned*)(slotB + 622592);
    unsigned short* hbA = (unsigned short*)(slotB + 884736);
    unsigned short* hbB = (unsigned short*)(slotB + 1064960);
    unsigned short* hdA = (unsigned short*)(slotB + 1245184);
    unsigned short* hdB = (unsigned short*)(slotB + 1261568);
    unsigned* barsS    = (unsigned*)(slotB + 1277952);  // 88 pair counters
    unsigned* barsD    = barsS + 88 * 16;               // 8 pair counters

    unsigned* Wsen     = (unsigned*)(ws + 44513280);
    unsigned* Wdoc     = (unsigned*)(ws + 44840960);

    dim3 blk(256);

    // D1: gather + bf16 casts
    prep_cast<<<dim3((N0 + N1 + N2 + 255) / 256), blk, 0, stream>>>(
        input_ids, titles, emb, sen_wih_f, sen_wih_b, doc_wih_f, doc_wih_b,
        Abf, Wsen, Wdoc);

    // D2: sentence+title input projection
    proj_mfma<<<dim3(158, 16), blk, 0, stream>>>(
        (const unsigned short*)Abf, 20160, 320,
        (const unsigned short*)Wsen, sen_b_f, sen_b_b, xw_all);

    // bars zero + Whh bf16 cast (slot B dead after D2)
    hipMemsetAsync(barsS, 0, (88 + 8) * 16 * sizeof(unsigned), stream);
    prep_whh<<<dim3(2048), blk, 0, stream>>>(
        sen_whh_f, sen_whh_b, doc_whh_f, doc_whh_b, WhhSbf, WhhDbf);

    // D3: persistent sentence/heading BiLSTM
    lstm_sen2b<<<dim3(176), dim3(512), 0, stream>>>(
        xw_all, xw_head, (const unsigned short*)WhhSbf, hbA, hbB,
        sentences, headings, barsS);

    // D4: SourceBias (url-grouped)
    source_bias_g<<<dim3(64, 8), blk, 0, stream>>>(
        sentences, urls, trans, sb_bias, biasedBf);

    // D5: document input projection
    proj_mfma<<<dim3(5, 16), blk, 0, stream>>>(
        (const unsigned short*)biasedBf, 640, 512,
        (const unsigned short*)Wdoc, doc_b_f, doc_b_b, xw_doc);

    // D6: persistent document BiLSTM
    lstm_doc2b<<<dim3(16), dim3(512), 0, stream>>>(
        xw_doc, (const unsigned short*)WhhDbf, hdA, hdB, documents, barsD);

    // D7: attention + heads (attn_v fused)
    attn_heads<<<dim3(64), blk, 0, stream>>>(documents, attn_W, headings, attn_b,
                                             bias_W1, bias_b1, bias_W2, bias_b2,
                                             truth_W1, truth_b1, truth_W2, truth_b2,
                                             out);
}

// Round 9
// 520.845 us; speedup vs baseline: 9.9901x; 1.0164x over previous
//
#include <hip/hip_runtime.h>
#include <cstddef>

typedef short bf16x8 __attribute__((ext_vector_type(8)));
typedef float f32x4 __attribute__((ext_vector_type(4)));

// fast sigmoid/tanh via v_exp_f32 + v_rcp_f32 (~1e-7 abs err; validated R4-R8:
// absmax identical to libm build)
__device__ __forceinline__ float sigm(float x) {
    return __builtin_amdgcn_rcpf(1.f + __expf(-x));
}
__device__ __forceinline__ float ftanh(float x) {
    float e = __expf(2.f * x);
    return 1.f - 2.f * __builtin_amdgcn_rcpf(e + 1.f);
}

// f32 -> bf16 (round to nearest even)
__device__ __forceinline__ unsigned short f2bf(float f) {
    union { float f; unsigned u; } v; v.f = f;
    return (unsigned short)((v.u + 0x7FFFu + ((v.u >> 16) & 1u)) >> 16);
}

// ============================================================================
// prep_all: ALL bf16 prep in ONE dispatch (prep_cast + prep_whh + bars zero).
//  region0: Abf[20160][320bf16] = emb rows gathered by ids(19200)+titles(960)
//  region1: Wsen[2048][320bf16] = [sen_wih_f | sen_wih_b] (K 300 -> 320 pad)
//  region2: Wdoc[2048][512bf16] = [doc_wih_f | doc_wih_b]
//  region3: WhhS/WhhD bf16 casts (row-major [dir][1024][256])
//  bars: first 1536 threads zero the pair counters.
// ============================================================================
#define N0 (20160 * 160)
#define N1 (2048 * 160)
#define N2 (2048 * 256)
#define NP (N0 + N1 + N2)
#define NW 524288

__global__ __launch_bounds__(256) void prep_all(
    const int* __restrict__ ids, const int* __restrict__ titles,
    const float* __restrict__ emb,
    const float* __restrict__ swf, const float* __restrict__ swb,
    const float* __restrict__ dwf, const float* __restrict__ dwb,
    const float* __restrict__ swhf, const float* __restrict__ swhb,
    const float* __restrict__ dwhf, const float* __restrict__ dwhb,
    unsigned* __restrict__ Abf, unsigned* __restrict__ Wsen,
    unsigned* __restrict__ Wdoc,
    unsigned* __restrict__ WS, unsigned* __restrict__ WD,
    unsigned* __restrict__ bars)
{
    int idx = blockIdx.x * 256 + threadIdx.x;
    if (idx < 1536) bars[idx] = 0u;           // 96 counters x 16-uint stride
    if (idx < N0) {
        int row = idx / 160, kk = idx - row * 160;
        int id = (row < 19200) ? ids[row] : titles[row - 19200];
        float a = 0.f, b = 0.f;
        if (kk < 150) {
            const float* s = emb + (size_t)id * 300 + kk * 2;
            a = s[0]; b = s[1];
        }
        Abf[idx] = (unsigned)f2bf(a) | ((unsigned)f2bf(b) << 16);
    } else if (idx < N0 + N1) {
        int j = idx - N0;
        int row = j / 160, kk = j - row * 160;
        const float* base = (row < 1024) ? swf + (size_t)row * 300
                                         : swb + (size_t)(row - 1024) * 300;
        float a = 0.f, b = 0.f;
        if (kk < 150) { a = base[kk * 2]; b = base[kk * 2 + 1]; }
        Wsen[j] = (unsigned)f2bf(a) | ((unsigned)f2bf(b) << 16);
    } else if (idx < NP) {
        int j = idx - N0 - N1;
        int row = j >> 8, kk = j & 255;
        const float* base = (row < 1024) ? dwf + (size_t)row * 512
                                         : dwb + (size_t)(row - 1024) * 512;
        Wdoc[j] = (unsigned)f2bf(base[kk * 2]) | ((unsigned)f2bf(base[kk * 2 + 1]) << 16);
    } else if (idx < NP + NW) {
        int j2 = idx - NP;
        const float* src; unsigned* dst;
        if (j2 < 262144) {
            int dir = j2 >> 17; int rem = j2 & 131071;
            src = (dir ? swhb : swhf) + ((size_t)(rem >> 7) * 256 + (rem & 127) * 2);
            dst = WS + j2;
        } else {
            int j = j2 - 262144; int dir = j >> 17; int rem = j & 131071;
            src = (dir ? dwhb : dwhf) + ((size_t)(rem >> 7) * 256 + (rem & 127) * 2);
            dst = WD + j;
        }
        *dst = (unsigned)f2bf(src[0]) | ((unsigned)f2bf(src[1]) << 16);
    }
}

// ============================================================================
// proj_mfma: out[M][2048] = Abf[M][Kp] @ Wbf^T + bias, output GATE-INTERLEAVED:
//   col = half*1024 + unit*4 + gate
// REG-STAGED DOUBLE-BUFFER: chunk k+1's global loads issue before chunk k's
// MFMAs, land in regs, ds_write after — load latency hides under compute;
// one barrier per chunk (was two + synchronous loads).
// ============================================================================
__global__ __launch_bounds__(256) void proj_mfma(
    const unsigned short* __restrict__ Abf, int M, int Kp,
    const unsigned short* __restrict__ Wbf,
    const float* __restrict__ bf_, const float* __restrict__ bb_,
    float* __restrict__ out)
{
    __shared__ unsigned short As[2][128 * 40];   // pitch 80B (16B aligned)
    __shared__ unsigned short Ws[2][128 * 40];
    const int tid  = threadIdx.x;
    const int lane = tid & 63;
    const int w    = tid >> 6;
    const int n    = lane & 15;
    const int quad = lane >> 4;
    const int bm   = blockIdx.x * 128;
    const int by   = blockIdx.y;              // 0..15
    const int half = by >> 3;
    const int ug32 = (by & 7) * 32;
    const unsigned short* Wb = Wbf + (size_t)half * 1024 * Kp;
    const float* biasp = half ? bb_ : bf_;

    // staging addresses: idx0 = tid (rows 0..63), idx1 = 256+tid (rows 64..127)
    const int r0i = tid >> 2,        q0 = tid & 3;
    const int r1i = (256 + tid) >> 2;
    int ga0 = bm + r0i; if (ga0 >= M) ga0 = M - 1;
    int ga1 = bm + r1i; if (ga1 >= M) ga1 = M - 1;
    const int wr0 = (r0i >> 5) * 256 + ug32 + (r0i & 31);   // gate*256 + unit
    const int wr1 = (r1i >> 5) * 256 + ug32 + (r1i & 31);
    const unsigned short* pA0 = Abf + (size_t)ga0 * Kp + q0 * 8;
    const unsigned short* pA1 = Abf + (size_t)ga1 * Kp + q0 * 8;
    const unsigned short* pW0 = Wb + (size_t)wr0 * Kp + q0 * 8;
    const unsigned short* pW1 = Wb + (size_t)wr1 * Kp + q0 * 8;
    const int la0 = r0i * 40 + q0 * 8;
    const int la1 = r1i * 40 + q0 * 8;

    f32x4 acc[2][8];
#pragma unroll
    for (int rt = 0; rt < 2; rt++)
#pragma unroll
        for (int ct = 0; ct < 8; ct++) acc[rt][ct] = (f32x4){0.f, 0.f, 0.f, 0.f};

    const int chunks = Kp >> 5;
    // prologue: chunk 0 -> buf 0
    {
        uint4 a0 = *(const uint4*)pA0;
        uint4 a1 = *(const uint4*)pA1;
        uint4 w0 = *(const uint4*)pW0;
        uint4 w1 = *(const uint4*)pW1;
        *(uint4*)&As[0][la0] = a0; *(uint4*)&As[0][la1] = a1;
        *(uint4*)&Ws[0][la0] = w0; *(uint4*)&Ws[0][la1] = w1;
    }
    __syncthreads();

    for (int kc = 0; kc < chunks; kc++) {
        const int b = kc & 1;
        uint4 a0, a1, w0, w1;
        if (kc + 1 < chunks) {
            const int k0 = (kc + 1) * 32;
            a0 = *(const uint4*)(pA0 + k0);
            a1 = *(const uint4*)(pA1 + k0);
            w0 = *(const uint4*)(pW0 + k0);
            w1 = *(const uint4*)(pW1 + k0);
        }
        bf16x8 Aq[2], Bq[8];
#pragma unroll
        for (int rt = 0; rt < 2; rt++)
            Aq[rt] = *(const bf16x8*)&As[b][((w * 2 + rt) * 16 + n) * 40 + quad * 8];
#pragma unroll
        for (int ct = 0; ct < 8; ct++)
            Bq[ct] = *(const bf16x8*)&Ws[b][(ct * 16 + n) * 40 + quad * 8];
#pragma unroll
        for (int rt = 0; rt < 2; rt++)
#pragma unroll
            for (int ct = 0; ct < 8; ct++)
                acc[rt][ct] = __builtin_amdgcn_mfma_f32_16x16x32_bf16(
                    Aq[rt], Bq[ct], acc[rt][ct], 0, 0, 0);
        if (kc + 1 < chunks) {
            *(uint4*)&As[b ^ 1][la0] = a0; *(uint4*)&As[b ^ 1][la1] = a1;
            *(uint4*)&Ws[b ^ 1][la0] = w0; *(uint4*)&Ws[b ^ 1][la1] = w1;
        }
        __syncthreads();
    }

#pragma unroll
    for (int s = 0; s < 2; s++) {
        const int uL = s * 16 + n;
        float b0 = biasp[ug32 + uL];
        float b1 = biasp[256 + ug32 + uL];
        float b2 = biasp[512 + ug32 + uL];
        float b3 = biasp[768 + ug32 + uL];
#pragma unroll
        for (int rt = 0; rt < 2; rt++) {
#pragma unroll
            for (int r = 0; r < 4; r++) {
                int row = bm + (w * 2 + rt) * 16 + quad * 4 + r;
                if (row >= M) continue;
                float4 o;
                o.x = acc[rt][0 + s][r] + b0;
                o.y = acc[rt][2 + s][r] + b1;
                o.z = acc[rt][4 + s][r] + b2;
                o.w = acc[rt][6 + s][r] + b3;
                *(float4*)(out + (size_t)row * 2048 + half * 1024 + (ug32 + uL) * 4) = o;
            }
        }
    }
}

__device__ __forceinline__ const float* sen_xbase(
    const float* xw, const float* xw_head, int grow_e, int t)
{
    if (grow_e < 640)       return xw + ((size_t)grow_e * 30 + t) * 2048;
    else if (grow_e < 1280) return xw + ((size_t)(grow_e - 640) * 30 + 29 - t) * 2048 + 1024;
    else if (grow_e < 1344) return xw_head + ((size_t)(grow_e - 1280) * 15 + t) * 2048;
    else                    return xw_head + ((size_t)(grow_e - 1344) * 15 + 14 - t) * 2048 + 1024;
}

// ============================================================================
// lstm_sen2c: R7/R8's verified pair-structure with ONE change: the xw(t+1)
// prefetch moves from BEFORE the sync (where the pre-signal __syncthreads'
// vmcnt drain made the partner-visible signal wait ~900cy for the HBM fetch)
// to BETWEEN signal and poll — prefetch latency now hides under the poll.
// ============================================================================
__global__ __launch_bounds__(512, 2) void lstm_sen2c(
    const float* __restrict__ xw, const float* __restrict__ xw_head,
    const unsigned short* __restrict__ WhhBf,     // [2][1024][256] bf16
    unsigned short* hbA, unsigned short* hbB,
    float* __restrict__ sentences, float* __restrict__ headings,
    unsigned* bars)
{
    const int tid  = threadIdx.x;
    const int lane = tid & 63;
    const int w    = tid >> 6;          // 0..7 (wave)
    const int n    = lane & 15;
    const int quad = lane >> 4;
    const int phys = blockIdx.x;        // 0..175
    const int g    = (phys & 7) + (phys >> 4) * 8;   // 0..87 (pair group)
    const int p    = (phys >> 3) & 1;                // unit-half
    const int r0   = g * 16;
    const bool bwd  = (r0 >= 640 && r0 < 1280) || (r0 >= 1344);
    const bool head = (r0 >= 1280);
    const int tEnd = head ? 15 : 30;
    unsigned* cnt = bars + g * 16;      // 64B-separated counters
    const unsigned short* Wd = WhhBf + (bwd ? (size_t)262144 : 0);

    __shared__ unsigned short Hs[2][16][264];   // pitch 528B
    __shared__ float G[16][516];                // pitch 2064B

    // B fragments: wave w owns local cols w*64 + ct*16 + n
    bf16x8 Bf[4][8];
#pragma unroll
    for (int ct = 0; ct < 4; ct++) {
        const int c    = ct * 16 + n;
        const int unit = p * 128 + w * 16 + (c >> 2);
        const int wrow = (c & 3) * 256 + unit;
        const unsigned short* wr = Wd + (size_t)wrow * 256;
#pragma unroll
        for (int ks = 0; ks < 8; ks++)
            Bf[ct][ks] = *(const bf16x8*)(wr + ks * 32 + quad * 8);
    }

    // zero h(t=0)
    for (int i = tid; i < 16 * 264; i += 512) ((unsigned short*)Hs[0])[i] = 0;

    const int rE  = tid & 15;            // row within group
    const int iE  = tid >> 4;            // 0..31
    const int ug4 = p * 128 + iE * 4;    // global unit base (4 units/thread)
    const int grow_e = r0 + rE;
    float cr[4] = {0.f, 0.f, 0.f, 0.f};

    // pointer-stepped xw prefetch
    const float* xptr = sen_xbase(xw, xw_head, grow_e, 0) + (size_t)ug4 * 4;
    const long long xstep = bwd ? -2048 : 2048;
    float4 xv[4];
    { const float4* xp = (const float4*)xptr;
      xv[0] = xp[0]; xv[1] = xp[1]; xv[2] = xp[2]; xv[3] = xp[3]; }

    // final h destination
    float* fdst;
    if (!head) fdst = sentences + (size_t)(bwd ? grow_e - 640 : grow_e) * 512
                      + (bwd ? 256 : 0) + ug4;
    else       fdst = headings + (size_t)(grow_e - (bwd ? 1344 : 1280)) * 512
                      + (bwd ? 256 : 0) + ug4;

    __syncthreads();

    for (int t = 0; t < tEnd; t++) {
        const int cur = t & 1;
        unsigned short* hq = (t & 1) ? hbA : hbB;

        // ---- hidden GEMM: G[0..15][own 512 cols] = h(t) @ Whh-half ----
        {
            bf16x8 Af[8];
#pragma unroll
            for (int ks = 0; ks < 8; ks++)
                Af[ks] = *(const bf16x8*)&Hs[cur][n][ks * 32 + quad * 8];
            f32x4 acc[4];
#pragma unroll
            for (int ct = 0; ct < 4; ct++) acc[ct] = (f32x4){0.f, 0.f, 0.f, 0.f};
#pragma unroll
            for (int ks = 0; ks < 8; ks++)
#pragma unroll
                for (int ct = 0; ct < 4; ct++)
                    acc[ct] = __builtin_amdgcn_mfma_f32_16x16x32_bf16(
                        Af[ks], Bf[ct][ks], acc[ct], 0, 0, 0);
#pragma unroll
            for (int ct = 0; ct < 4; ct++)
#pragma unroll
                for (int r = 0; r < 4; r++)
                    G[quad * 4 + r][w * 64 + ct * 16 + n] = acc[ct][r];
        }
        __syncthreads();

        // ---- gate epilogue: 4 (row,unit) pairs per thread ----
        {
            const float4* Gp = (const float4*)&G[rE][iE * 16];
            unsigned long long hpack = 0ull;
            float hout[4];
#pragma unroll
            for (int q2 = 0; q2 < 4; q2++) {
                float4 gv = Gp[q2];
                float gi = gv.x + xv[q2].x;
                float gf = gv.y + xv[q2].y;
                float gg = gv.z + xv[q2].z;
                float go = gv.w + xv[q2].w;
                float cn = sigm(gf) * cr[q2] + sigm(gi) * ftanh(gg);
                float hn = sigm(go) * ftanh(cn);
                cr[q2] = cn; hout[q2] = hn;
                hpack |= ((unsigned long long)f2bf(hn)) << (16 * q2);
            }
            const int nxt = cur ^ 1;
            *(unsigned long long*)&Hs[nxt][rE][ug4] = hpack;   // own half -> LDS
            __hip_atomic_store((unsigned long long*)(hq + (size_t)grow_e * 256 + ug4),
                               hpack, __ATOMIC_RELAXED, __HIP_MEMORY_SCOPE_AGENT);
            if (t == tEnd - 1) *(float4*)fdst = *(float4*)hout;
        }

        if (t + 1 < tEnd) {
            // signal: drain h-stores (only outstanding vmem at this point),
            // bump counter — xw prefetch NOT yet issued, so drain is cheap.
            __syncthreads();
            if (tid == 0)
                __hip_atomic_fetch_add(cnt, 1u, __ATOMIC_RELAXED,
                                       __HIP_MEMORY_SCOPE_AGENT);
            // prefetch next step's xw — latency hides under the poll
            xptr += xstep;
            const float4* xp = (const float4*)xptr;
            xv[0] = xp[0]; xv[1] = xp[1]; xv[2] = xp[2]; xv[3] = xp[3];
            if (tid == 0) {
                const unsigned tgt = 2u * (unsigned)(t + 1);
                while (__hip_atomic_load(cnt, __ATOMIC_RELAXED,
                                         __HIP_MEMORY_SCOPE_AGENT) < tgt)
                    __builtin_amdgcn_s_sleep(1);
            }
            __syncthreads();
            // partner half -> Hs[nxt]: one 8B chunk per thread (16 rows x 32)
            {
                const int nxt   = cur ^ 1;
                const int row   = tid >> 5;
                const int chunk = tid & 31;
                const int pp    = p ^ 1;
                unsigned long long v = __hip_atomic_load(
                    (const unsigned long long*)(hq + (size_t)(r0 + row) * 256
                                                + pp * 128 + chunk * 4),
                    __ATOMIC_RELAXED, __HIP_MEMORY_SCOPE_AGENT);
                *(unsigned long long*)&Hs[nxt][row][pp * 128 + chunk * 4] = v;
            }
            __syncthreads();
        }
    }
}

// ============================================================================
// lstm_doc2c: same structure + same prefetch reorder. Grid 16 x 512.
// ============================================================================
__global__ __launch_bounds__(512, 2) void lstm_doc2c(
    const float* __restrict__ xw,
    const unsigned short* __restrict__ WhhBf,     // [2][1024][256] bf16
    unsigned short* hdA, unsigned short* hdB,
    float* __restrict__ documents,
    unsigned* bars)
{
    const int tid  = threadIdx.x;
    const int lane = tid & 63;
    const int w    = tid >> 6;
    const int n    = lane & 15;
    const int quad = lane >> 4;
    const int phys = blockIdx.x;        // 0..15
    const int g    = phys & 7;          // 0..7
    const int p    = (phys >> 3) & 1;
    const int r0   = g * 16;
    const bool bwd = (r0 >= 64);
    unsigned* cnt = bars + g * 16;
    const unsigned short* Wd = WhhBf + (bwd ? (size_t)262144 : 0);

    __shared__ unsigned short Hs[2][16][264];
    __shared__ float G[16][516];

    bf16x8 Bf[4][8];
#pragma unroll
    for (int ct = 0; ct < 4; ct++) {
        const int c    = ct * 16 + n;
        const int unit = p * 128 + w * 16 + (c >> 2);
        const int wrow = (c & 3) * 256 + unit;
        const unsigned short* wr = Wd + (size_t)wrow * 256;
#pragma unroll
        for (int ks = 0; ks < 8; ks++)
            Bf[ct][ks] = *(const bf16x8*)(wr + ks * 32 + quad * 8);
    }

    for (int i = tid; i < 16 * 264; i += 512) ((unsigned short*)Hs[0])[i] = 0;

    const int rE  = tid & 15;
    const int iE  = tid >> 4;
    const int ug4 = p * 128 + iE * 4;
    const int grow_e = r0 + rE;
    const int seq = bwd ? grow_e - 64 : grow_e;     // doc index
    float cr[4] = {0.f, 0.f, 0.f, 0.f};

    const float* xptr = (!bwd ? xw + (size_t)seq * 10 * 2048
                              : xw + ((size_t)seq * 10 + 9) * 2048 + 1024)
                        + (size_t)ug4 * 4;
    const long long xstep = bwd ? -2048 : 2048;
    float4 xv[4];
    { const float4* xp = (const float4*)xptr;
      xv[0] = xp[0]; xv[1] = xp[1]; xv[2] = xp[2]; xv[3] = xp[3]; }

    float* dptr = documents + (size_t)(seq * 10 + (bwd ? 9 : 0)) * 512
                  + (bwd ? 256 : 0) + ug4;
    const long long dstep = bwd ? -512 : 512;

    __syncthreads();

    for (int t = 0; t < 10; t++) {
        const int cur = t & 1;
        unsigned short* hq = (t & 1) ? hdA : hdB;

        {
            bf16x8 Af[8];
#pragma unroll
            for (int ks = 0; ks < 8; ks++)
                Af[ks] = *(const bf16x8*)&Hs[cur][n][ks * 32 + quad * 8];
            f32x4 acc[4];
#pragma unroll
            for (int ct = 0; ct < 4; ct++) acc[ct] = (f32x4){0.f, 0.f, 0.f, 0.f};
#pragma unroll
            for (int ks = 0; ks < 8; ks++)
#pragma unroll
                for (int ct = 0; ct < 4; ct++)
                    acc[ct] = __builtin_amdgcn_mfma_f32_16x16x32_bf16(
                        Af[ks], Bf[ct][ks], acc[ct], 0, 0, 0);
#pragma unroll
            for (int ct = 0; ct < 4; ct++)
#pragma unroll
                for (int r = 0; r < 4; r++)
                    G[quad * 4 + r][w * 64 + ct * 16 + n] = acc[ct][r];
        }
        __syncthreads();

        {
            const float4* Gp = (const float4*)&G[rE][iE * 16];
            unsigned long long hpack = 0ull;
            float hout[4];
#pragma unroll
            for (int q2 = 0; q2 < 4; q2++) {
                float4 gv = Gp[q2];
                float gi = gv.x + xv[q2].x;
                float gf = gv.y + xv[q2].y;
                float gg = gv.z + xv[q2].z;
                float go = gv.w + xv[q2].w;
                float cn = sigm(gf) * cr[q2] + sigm(gi) * ftanh(gg);
                float hn = sigm(go) * ftanh(cn);
                cr[q2] = cn; hout[q2] = hn;
                hpack |= ((unsigned long long)f2bf(hn)) << (16 * q2);
            }
            const int nxt = cur ^ 1;
            *(unsigned long long*)&Hs[nxt][rE][ug4] = hpack;
            __hip_atomic_store((unsigned long long*)(hq + (size_t)grow_e * 256 + ug4),
                               hpack, __ATOMIC_RELAXED, __HIP_MEMORY_SCOPE_AGENT);
            *(float4*)dptr = *(float4*)hout;
        }

        if (t < 9) {
            __syncthreads();
            if (tid == 0)
                __hip_atomic_fetch_add(cnt, 1u, __ATOMIC_RELAXED,
                                       __HIP_MEMORY_SCOPE_AGENT);
            xptr += xstep;  dptr += dstep;
            const float4* xp = (const float4*)xptr;
            xv[0] = xp[0]; xv[1] = xp[1]; xv[2] = xp[2]; xv[3] = xp[3];
            if (tid == 0) {
                const unsigned tgt = 2u * (unsigned)(t + 1);
                while (__hip_atomic_load(cnt, __ATOMIC_RELAXED,
                                         __HIP_MEMORY_SCOPE_AGENT) < tgt)
                    __builtin_amdgcn_s_sleep(1);
            }
            __syncthreads();
            {
                const int nxt   = cur ^ 1;
                const int row   = tid >> 5;
                const int chunk = tid & 31;
                const int pp    = p ^ 1;
                unsigned long long v = __hip_atomic_load(
                    (const unsigned long long*)(hq + (size_t)(r0 + row) * 256
                                                + pp * 128 + chunk * 4),
                    __ATOMIC_RELAXED, __HIP_MEMORY_SCOPE_AGENT);
                *(unsigned long long*)&Hs[nxt][row][pp * 128 + chunk * 4] = v;
            }
            __syncthreads();
        }
    }
}

// ============================================================================
// source_bias_g: URL-GROUPED SourceBias (verified R8). Grid (64, 8), 256 thr.
// ============================================================================
__global__ __launch_bounds__(256) void source_bias_g(
    const float* __restrict__ sentences, const int* __restrict__ urls,
    const float* __restrict__ trans, const float* __restrict__ sb_bias,
    unsigned* __restrict__ biasedBf)
{
    const int u   = blockIdx.x;          // url
    const int s   = blockIdx.y;          // col-slice: cols [s*64, s*64+64)
    const int tid = threadIdx.x;
    __shared__ int   toks[640];
    __shared__ int   cntS;
    __shared__ float sv[16][516];        // 16 tokens x 512 f32 (pitch 2064B)
    __shared__ float red[4][64][17];     // dq x localcol x token (padded)

    if (tid == 0) cntS = 0;
    __syncthreads();
    for (int i = tid; i < 640; i += 256) {
        if (urls[i] == u) {
            int slot = atomicAdd(&cntS, 1);
            toks[slot] = i;
        }
    }
    __syncthreads();
    const int cnt = cntS;
    const int dq  = tid >> 6;            // wave index 0..3 (d-stripe)
    const int eL  = tid & 63;            // local col
    const int e   = s * 64 + eL;
    const float* Tm = trans + (size_t)u * 512 * 512;

    for (int t0 = 0; t0 < cnt; t0 += 16) {
        const int nt = (cnt - t0 < 16) ? (cnt - t0) : 16;
        // stage sentence rows (f32, coalesced float4)
        for (int i = tid; i < 16 * 128; i += 256) {
            int r = i >> 7, c4 = i & 127;
            float4 v4;
            if (r < nt) v4 = *(const float4*)(sentences + (size_t)toks[t0 + r] * 512 + c4 * 4);
            else        v4 = (float4){0.f, 0.f, 0.f, 0.f};
            *(float4*)&sv[r][c4 * 4] = v4;
        }
        __syncthreads();

        float ax[16];
#pragma unroll
        for (int r = 0; r < 16; r++) ax[r] = 0.f;
        for (int it = 0; it < 128; it++) {
            const int d = it * 4 + dq;
            float wv = Tm[(size_t)d * 512 + e];
#pragma unroll
            for (int r = 0; r < 16; r++) ax[r] += sv[r][d] * wv;
        }
#pragma unroll
        for (int r = 0; r < 16; r++) red[dq][eL][r] = ax[r];
        __syncthreads();

        // outputs: nt tokens x 32 u32-pairs for this slice
        for (int o = tid; o < nt * 32; o += 256) {
            int t  = o >> 5, ep = o & 31;
            int c0 = ep * 2, c1 = c0 + 1;
            float x0 = red[0][c0][t] + red[1][c0][t] + red[2][c0][t] + red[3][c0][t];
            float x1 = red[0][c1][t] + red[1][c1][t] + red[2][c1][t] + red[3][c1][t];
            int tkn = toks[t0 + t];
            int eg  = s * 32 + ep;       // u32 index within the 256-wide row
            const float2 bv = ((const float2*)(sb_bias + (size_t)u * 512))[eg];
            float xx = ftanh(x0 + bv.x), yy = ftanh(x1 + bv.y);
            biasedBf[(size_t)tkn * 256 + eg] =
                (unsigned)f2bf(xx) | ((unsigned)f2bf(yy) << 16);
        }
        __syncthreads();                 // sv/red reuse next tile
    }
}

// ============================================================================
// attn_heads (attn_v fused, verified R8): scores -> softmax -> doc_rep -> MLPs.
// ============================================================================
__global__ __launch_bounds__(256) void attn_heads(
    const float* __restrict__ documents, const float* __restrict__ W,
    const float* __restrict__ headings,
    const float* __restrict__ attn_b,
    const float* __restrict__ bW1, const float* __restrict__ bb1,
    const float* __restrict__ bW2, const float* __restrict__ bb2,
    const float* __restrict__ tW1, const float* __restrict__ tb1,
    const float* __restrict__ tW2, const float* __restrict__ tb2,
    float* __restrict__ out)
{
    const int b = blockIdx.x, tid = threadIdx.x;
    const int lane = tid & 63, wv_ = tid >> 6;
    __shared__ float hh[512], vv[512], dr[512], h1s[256], t1s[256], sw[12], lg[5];
    for (int i = tid; i < 512; i += 256) hh[i] = headings[(size_t)b * 512 + i];
    __syncthreads();
    // v[d] = sum_e W[d][e] * hh[e]
    for (int d = tid; d < 512; d += 256) {
        float a = 0.f;
        const float* wr = W + (size_t)d * 512;
        for (int e2 = 0; e2 < 512; e2++) a += wr[e2] * hh[e2];
        vv[d] = a;
    }
    __syncthreads();
    for (int q = 0; q < 3; q++) {
        int s = q * 4 + wv_;
        float p = 0.f;
        if (s < 10) {
            const float* dp = documents + (size_t)(b * 10 + s) * 512;
            for (int d = lane; d < 512; d += 64) p += dp[d] * vv[d];
        }
#pragma unroll
        for (int off = 32; off > 0; off >>= 1) p += __shfl_down(p, off, 64);
        if (s < 10 && lane == 0) sw[s] = p + attn_b[0];
    }
    __syncthreads();
    if (tid == 0) {
        float mx = sw[0];
        for (int s = 1; s < 10; s++) mx = fmaxf(mx, sw[s]);
        float sum = 0.f;
        for (int s = 0; s < 10; s++) { sw[s] = __expf(sw[s] - mx); sum += sw[s]; }
        for (int s = 0; s < 10; s++) sw[s] /= sum;
    }
    __syncthreads();
    for (int d = tid; d < 512; d += 256) {
        float a = 0.f;
#pragma unroll
        for (int s = 0; s < 10; s++) a += sw[s] * documents[(size_t)(b * 10 + s) * 512 + d];
        dr[d] = a;
    }
    __syncthreads();
    {
        float a = bb1[tid], a2 = tb1[tid];
        const float* w1 = bW1 + (size_t)tid * 512;
        const float* w2 = tW1 + (size_t)tid * 512;
        for (int k = 0; k < 512; k++) { float x = dr[k]; a += x * w1[k]; a2 += x * w2[k]; }
        h1s[tid] = ftanh(a); t1s[tid] = ftanh(a2);
    }
    __syncthreads();
    if (tid < 5) {
        float a = bb2[tid];
        const float* wp = bW2 + (size_t)tid * 256;
        for (int k = 0; k < 256; k++) a += h1s[k] * wp[k];
        lg[tid] = ftanh(a);
    }
    if (tid == 32) {
        float a = tb2[0];
        for (int k = 0; k < 256; k++) a += t1s[k] * tW2[k];
        out[320 + b] = sigm(ftanh(a));
    }
    __syncthreads();
    if (tid == 0) {
        float mx = lg[0];
        for (int j = 1; j < 5; j++) mx = fmaxf(mx, lg[j]);
        float sum = 0.f, e[5];
        for (int j = 0; j < 5; j++) { e[j] = __expf(lg[j] - mx); sum += e[j]; }
        for (int j = 0; j < 5; j++) out[b * 5 + j] = e[j] / sum;
    }
}

extern "C" void kernel_launch(void* const* d_in, const int* in_sizes, int n_in,
                              void* d_out, int out_size, void* d_ws, size_t ws_size,
                              hipStream_t stream)
{
    (void)in_sizes; (void)n_in; (void)out_size; (void)ws_size;
    const int*   input_ids = (const int*)d_in[0];
    const int*   urls      = (const int*)d_in[1];
    const int*   titles    = (const int*)d_in[2];
    const float* emb       = (const float*)d_in[3];
    const float* sen_wih_f = (const float*)d_in[4];
    const float* sen_whh_f = (const float*)d_in[5];
    const float* sen_b_f   = (const float*)d_in[6];
    const float* sen_wih_b = (const float*)d_in[7];
    const float* sen_whh_b = (const float*)d_in[8];
    const float* sen_b_b   = (const float*)d_in[9];
    const float* trans     = (const float*)d_in[10];
    const float* sb_bias   = (const float*)d_in[11];
    const float* doc_wih_f = (const float*)d_in[12];
    const float* doc_whh_f = (const float*)d_in[13];
    const float* doc_b_f   = (const float*)d_in[14];
    const float* doc_wih_b = (const float*)d_in[15];
    const float* doc_whh_b = (const float*)d_in[16];
    const float* doc_b_b   = (const float*)d_in[17];
    const float* attn_W    = (const float*)d_in[18];
    const float* attn_b    = (const float*)d_in[19];
    const float* bias_W1   = (const float*)d_in[20];
    const float* bias_b1   = (const float*)d_in[21];
    const float* bias_W2   = (const float*)d_in[22];
    const float* bias_b2   = (const float*)d_in[23];
    const float* truth_W1  = (const float*)d_in[24];
    const float* truth_b1  = (const float*)d_in[25];
    const float* truth_W2  = (const float*)d_in[26];
    const float* truth_b2  = (const float*)d_in[27];
    float* out = (float*)d_out;

    float* ws = (float*)d_ws;
    float* xw_all      = ws;
    float* xw_head     = xw_all + (size_t)19200 * 2048;
    unsigned* biasedBf = (unsigned*)(ws + 0);
    float* xw_doc      = ws + 163840;
    float* documents   = ws + 1474560;

    float* slotB       = ws + 41287680;
    unsigned* Abf      = (unsigned*)slotB;
    float* sentences   = slotB;
    float* headings    = slotB + 327680;
    unsigned* WhhSbf   = (unsigned*)(slotB + 360448);   // [2][1024][128] u32
    unsigned* WhhDbf   = (unsigned*)(slotB + 622592);
    unsigned short* hbA = (unsigned short*)(slotB + 884736);
    unsigned short* hbB = (unsigned short*)(slotB + 1064960);
    unsigned short* hdA = (unsigned short*)(slotB + 1245184);
    unsigned short* hdB = (unsigned short*)(slotB + 1261568);
    unsigned* barsS    = (unsigned*)(slotB + 1277952);  // 88 pair counters
    unsigned* barsD    = barsS + 88 * 16;               // 8 pair counters

    unsigned* Wsen     = (unsigned*)(ws + 44513280);
    unsigned* Wdoc     = (unsigned*)(ws + 44840960);

    dim3 blk(256);

    // D1: gather + ALL bf16 casts + bars zero (one dispatch)
    prep_all<<<dim3((NP + NW + 255) / 256), blk, 0, stream>>>(
        input_ids, titles, emb, sen_wih_f, sen_wih_b, doc_wih_f, doc_wih_b,
        sen_whh_f, sen_whh_b, doc_whh_f, doc_whh_b,
        Abf, Wsen, Wdoc, WhhSbf, WhhDbf, barsS);

    // D2: sentence+title input projection (reg-staged double-buffer)
    proj_mfma<<<dim3(158, 16), blk, 0, stream>>>(
        (const unsigned short*)Abf, 20160, 320,
        (const unsigned short*)Wsen, sen_b_f, sen_b_b, xw_all);

    // D3: persistent sentence/heading BiLSTM
    lstm_sen2c<<<dim3(176), dim3(512), 0, stream>>>(
        xw_all, xw_head, (const unsigned short*)WhhSbf, hbA, hbB,
        sentences, headings, barsS);

    // D4: SourceBias (url-grouped)
    source_bias_g<<<dim3(64, 8), blk, 0, stream>>>(
        sentences, urls, trans, sb_bias, biasedBf);

    // D5: document input projection
    proj_mfma<<<dim3(5, 16), blk, 0, stream>>>(
        (const unsigned short*)biasedBf, 640, 512,
        (const unsigned short*)Wdoc, doc_b_f, doc_b_b, xw_doc);

    // D6: persistent document BiLSTM
    lstm_doc2c<<<dim3(16), dim3(512), 0, stream>>>(
        xw_doc, (const unsigned short*)WhhDbf, hdA, hdB, documents, barsD);

    // D7: attention + heads (attn_v fused)
    attn_heads<<<dim3(64), blk, 0, stream>>>(documents, attn_W, headings, attn_b,
                                             bias_W1, bias_b1, bias_W2, bias_b2,
                                             truth_W1, truth_b1, truth_W2, truth_b2,
                                             out);
}